// Round 1
// 266.262 us; speedup vs baseline: 1.0003x; 1.0003x over previous
//
#include <hip/hip_runtime.h>

// IPLS partial_fit (n > BURN_IN). Gram-reformulated.
// R6: x-side Gram rebuilt on matrix cores. 2-term bf16 split (hi = truncated
// top16, lo = RNE bf16 of residual, all 4 cross MFMAs) reconstructs fp32
// products to ~2^-17 relative. M=48 rows [xc,P0..31,pad] x N=80 cols
// [xc,P0..31,Wz0..31,pad], mfma_f32_16x16x32_bf16, 512 K-slice blocks x
// 4 chunks of 128. LDS 41KB (hi/lo planes, XOR-swizzled (row&7)<<4 so both
// staging writes and frag ds_read_b128 are <=2-way) -> 3 blocks/CU.
// diag(Wz.Wz) via LDS atomics in the conversion pass (MFMA tile doesn't
// cover it). reduce1+reduce2 replaced by one chunked-atomic reduce.
// solve re-indexed (row stride 68 kept; dS from diag slot). out_kernel as R5.

#define NF 262144
#define NT 8192
#define NL 32
#define GYS 36
#define LDSW 260       // y-side row stride (floats): 256 + 4 pad

#define NBX 512        // x-side K-slice blocks
#define KS  512        // K elems per block
#define CHK 128        // K elems per chunk (LDS resident)
#define NCHK (KS/CHK)  // 4
#define GXW 68         // stored Gram row stride (cols 0..64 used)
#define PBE 2276       // per-block partial: 33*68 + 32 diag
#define DIAG 2244      // 33*68

#define WS_PART 0
#define WS_GY   (NBX*PBE)            // 1165312
#define WS_GX   (WS_GY + GYS*GYS)    // 1166608
#define WS_COEF (WS_GX + PBE)        // 1168884  (+3168 -> 1172052 floats, 4.7MB)

#define OUT_MU_X 0
#define OUT_MU_Y 262144
#define OUT_U    270336
#define OUT_WZ   270368
#define OUT_CZ   8658976
#define OUT_TSS  8921120
#define OUT_BZ   8921152
#define OUT_P    8921184

typedef __attribute__((ext_vector_type(8))) short bf16x8;
typedef __attribute__((ext_vector_type(4))) float f32x4;

__device__ __forceinline__ float4 ld4(const float* p) { return *(const float4*)p; }

__device__ __forceinline__ unsigned int f2bf_rne(float f) {
  unsigned int t = __float_as_uint(f);
  t += 0x7FFFu + ((t >> 16) & 1u);
  return t >> 16;
}

__global__ __launch_bounds__(320) void gram_kernel(
    const float* __restrict__ x, const float* __restrict__ y,
    const float* __restrict__ mux, const float* __restrict__ muy,
    const float* __restrict__ Wz, const float* __restrict__ Cz,
    const float* __restrict__ P, const int* __restrict__ np,
    float* __restrict__ ws)
{
  __shared__ __align__(16) char smem[80 * CHK * 4 + 128];  // hi+lo planes + diag
  const int tid = threadIdx.x;
  const int b = blockIdx.x;
  const float n1 = (float)(np[0] + 1);
  const float cmu = n1 / (n1 + 1.0f);   // xc = cmu*(x - mu_old)

  if (b < NBX) {
    // ---- x-side: bf16-split MFMA SYRK slice ----
    char* hB = smem;                        // hi plane: [80][128] bf16
    char* lB = smem + 80 * CHK * 2;         // lo plane
    float* sdiag = (float*)(smem + 80 * CHK * 4);

    if (tid < 32) sdiag[tid] = 0.f;
    {  // zero pad rows 65..79 (both planes), once; stays zero across chunks
      unsigned int* hz = (unsigned int*)hB;
      unsigned int* lz = (unsigned int*)lB;
      for (int i = tid; i < 960; i += 320) { hz[65 * 64 + i] = 0u; lz[65 * 64 + i] = 0u; }
    }

    f32x4 acc0 = {0.f, 0.f, 0.f, 0.f};
    f32x4 acc1 = acc0, acc2 = acc0;
    const int lane = tid & 63;
    const int w = tid >> 6;            // wave = N-tile 0..4 (cols w*16..w*16+15)
    const int col16 = lane & 15;
    const int kgrp = lane >> 4;        // 0..3
    const int swz = (col16 & 7) << 4;  // (row&7)<<4; row%8 == col16%8 for all frags

    for (int c = 0; c < NCHK; ++c) {
      __syncthreads();                 // prev compute done before overwrite
      const int kb = b * KS + c * CHK;
      // stage: 65 rows x 32 float4 = 2080 loads; convert fp32 -> bf16 hi/lo
#pragma unroll
      for (int it = 0; it < 7; ++it) {
        int idx = tid + it * 320;
        if (idx < 2080) {
          int row = idx >> 5;
          int c4 = idx & 31;
          int k = kb + c4 * 4;
          float4 v;
          if (row == 0) {
            float4 xv = ld4(x + k), mv = ld4(mux + k);
            v.x = cmu * (xv.x - mv.x); v.y = cmu * (xv.y - mv.y);
            v.z = cmu * (xv.z - mv.z); v.w = cmu * (xv.w - mv.w);
          } else if (row < 33) {
            v = ld4(P + (size_t)(row - 1) * NF + k);
          } else {
            v = ld4(Wz + (size_t)(row - 33) * NF + k);
            atomicAdd(&sdiag[row - 33], v.x * v.x + v.y * v.y + v.z * v.z + v.w * v.w);
          }
          unsigned int b0 = __float_as_uint(v.x), b1 = __float_as_uint(v.y);
          unsigned int b2 = __float_as_uint(v.z), b3 = __float_as_uint(v.w);
          float h0 = __uint_as_float(b0 & 0xFFFF0000u);
          float h1 = __uint_as_float(b1 & 0xFFFF0000u);
          float h2 = __uint_as_float(b2 & 0xFFFF0000u);
          float h3 = __uint_as_float(b3 & 0xFFFF0000u);
          uint2 hw, lw;
          hw.x = (b0 >> 16) | ((b1 >> 16) << 16);
          hw.y = (b2 >> 16) | ((b3 >> 16) << 16);
          lw.x = f2bf_rne(v.x - h0) | (f2bf_rne(v.y - h1) << 16);
          lw.y = f2bf_rne(v.z - h2) | (f2bf_rne(v.w - h3) << 16);
          int off = ((row << 8) + (c4 << 3)) ^ ((row & 7) << 4);
          *(uint2*)(hB + off) = hw;
          *(uint2*)(lB + off) = lw;
        }
      }
      __syncthreads();
      // compute: 4 K-steps of 32; per step: 8 ds_read_b128 + 12 MFMA
#pragma unroll
      for (int s = 0; s < 4; ++s) {
        const int kbyte = s * 64 + kgrp * 16;
        const int oa = ((col16 << 8) + kbyte) ^ swz;   // M-tile 0 (rows 0..15)
        const int ob = oa + (w << 12);                 // N-tile w
        bf16x8 bh = *(const bf16x8*)(hB + ob);
        bf16x8 bl = *(const bf16x8*)(lB + ob);
        bf16x8 a0h = *(const bf16x8*)(hB + oa);
        bf16x8 a0l = *(const bf16x8*)(lB + oa);
        acc0 = __builtin_amdgcn_mfma_f32_16x16x32_bf16(a0h, bh, acc0, 0, 0, 0);
        acc0 = __builtin_amdgcn_mfma_f32_16x16x32_bf16(a0h, bl, acc0, 0, 0, 0);
        acc0 = __builtin_amdgcn_mfma_f32_16x16x32_bf16(a0l, bh, acc0, 0, 0, 0);
        acc0 = __builtin_amdgcn_mfma_f32_16x16x32_bf16(a0l, bl, acc0, 0, 0, 0);
        bf16x8 a1h = *(const bf16x8*)(hB + oa + 4096);  // rows 16..31
        bf16x8 a1l = *(const bf16x8*)(lB + oa + 4096);
        acc1 = __builtin_amdgcn_mfma_f32_16x16x32_bf16(a1h, bh, acc1, 0, 0, 0);
        acc1 = __builtin_amdgcn_mfma_f32_16x16x32_bf16(a1h, bl, acc1, 0, 0, 0);
        acc1 = __builtin_amdgcn_mfma_f32_16x16x32_bf16(a1l, bh, acc1, 0, 0, 0);
        acc1 = __builtin_amdgcn_mfma_f32_16x16x32_bf16(a1l, bl, acc1, 0, 0, 0);
        bf16x8 a2h = *(const bf16x8*)(hB + oa + 8192);  // rows 32..47 (row 32 = P31)
        bf16x8 a2l = *(const bf16x8*)(lB + oa + 8192);
        acc2 = __builtin_amdgcn_mfma_f32_16x16x32_bf16(a2h, bh, acc2, 0, 0, 0);
        acc2 = __builtin_amdgcn_mfma_f32_16x16x32_bf16(a2h, bl, acc2, 0, 0, 0);
        acc2 = __builtin_amdgcn_mfma_f32_16x16x32_bf16(a2l, bh, acc2, 0, 0, 0);
        acc2 = __builtin_amdgcn_mfma_f32_16x16x32_bf16(a2l, bl, acc2, 0, 0, 0);
      }
    }
    // partial write: D layout col=lane&15, row=(lane>>4)*4+reg [m89]
    float* PB = ws + WS_PART + (size_t)b * PBE;
    const int vcol = w * 16 + col16;
    if (vcol < 65) {
#pragma unroll
      for (int r2 = 0; r2 < 4; ++r2) {
        int u = kgrp * 4 + r2;
        PB[u * GXW + vcol] = acc0[r2];              // rows 0..15
        PB[(16 + u) * GXW + vcol] = acc1[r2];       // rows 16..31
        if (16 + u == 16) PB[32 * GXW + vcol] = acc2[r2];  // only row 32 needed
      }
    }
    if (tid < 32) PB[DIAG + tid] = sdiag[tid];      // atomics drained by last barrier
  } else {
    // ---- y-side: unchanged R5 path (36 rows [yc, Cz_0..31, zeros]) ----
    float* lds = (float*)smem;   // 36*260*4 = 37.4KB <= 41KB alias
    float* GY = ws + WS_GY;
    const int yb = b - NBX;
    int gu = 0, gv = 0; bool active = (tid < 45);
    if (active) {
      int pp = tid;
      for (int g = 0; g < 9; ++g) {
        int cnt = 9 - g;
        if (pp < cnt) { gu = g; gv = g + pp; break; }
        pp -= cnt;
      }
    }
    float acc[16];
#pragma unroll
    for (int i = 0; i < 16; ++i) acc[i] = 0.f;
    const int wb = yb * 256;
    for (int it = 0; it < 8; ++it) {
      int idx = tid + it * 320;
      if (idx < 2304) {
        int row = idx >> 6;
        int c4 = idx & 63;
        int k = wb + c4 * 4;
        float4 v;
        if (row == 0) {
          float4 yv = ld4(y + k), mv = ld4(muy + k);
          v.x = cmu * (yv.x - mv.x); v.y = cmu * (yv.y - mv.y);
          v.z = cmu * (yv.z - mv.z); v.w = cmu * (yv.w - mv.w);
        } else if (row < 33) {
          v = ld4(Cz + (size_t)(row - 1) * NT + k);
        } else {
          v = make_float4(0.f, 0.f, 0.f, 0.f);
        }
        *(float4*)&lds[row * LDSW + c4 * 4] = v;
      }
    }
    __syncthreads();
    if (active) {
      const int ub = 4 * gu * LDSW, vb = 4 * gv * LDSW;
      for (int c = 0; c < 64; ++c) {
        float4 av[4], bv[4];
#pragma unroll
        for (int r = 0; r < 4; ++r) av[r] = *(const float4*)&lds[ub + r * LDSW + c * 4];
#pragma unroll
        for (int s = 0; s < 4; ++s) bv[s] = *(const float4*)&lds[vb + s * LDSW + c * 4];
#pragma unroll
        for (int r = 0; r < 4; ++r)
#pragma unroll
          for (int s = 0; s < 4; ++s)
            acc[r * 4 + s] += av[r].x * bv[s].x + av[r].y * bv[s].y +
                              av[r].z * bv[s].z + av[r].w * bv[s].w;
      }
#pragma unroll
      for (int r = 0; r < 4; ++r)
#pragma unroll
        for (int s = 0; s < 4; ++s) {
          int u = 4 * gu + r, v = 4 * gv + s;
          if (u < 33 && v < 33) {
            float val = acc[r * 4 + s];
            atomicAdd(&GY[u * GYS + v], val);
            if (gu != gv) atomicAdd(&GY[v * GYS + u], val);
          }
        }
    }
  }
}

// one-stage chunked reduce: 8 chunks x 64 blocks -> atomicAdd into GX
__global__ __launch_bounds__(256) void reduce_kernel(float* __restrict__ ws) {
  const int e = (blockIdx.x % 9) * 256 + threadIdx.x;
  const int c = blockIdx.x / 9;          // 0..7
  if (e < PBE) {
    const float* PB = ws + WS_PART + (size_t)(c * 64) * PBE + e;
    float s0 = 0.f, s1 = 0.f, s2 = 0.f, s3 = 0.f;
#pragma unroll
    for (int j = 0; j < 64; j += 4) {
      s0 += PB[(size_t)j * PBE];
      s1 += PB[(size_t)(j + 1) * PBE];
      s2 += PB[(size_t)(j + 2) * PBE];
      s3 += PB[(size_t)(j + 3) * PBE];
    }
    atomicAdd(ws + WS_GX + e, (s0 + s1) + (s2 + s3));
  }
}

// One wave: f64 scalar recurrences for all 32 components; Gram rows preloaded
// into registers; i-loop fully unrolled (compile-time __shfl indices).
// GX layout now 33x68 [xc,P | cols: xc,P,Wz] + diag(Wz.Wz) at DIAG.
__global__ void solve_kernel(const float* __restrict__ ws,
                             const float* __restrict__ u_in,
                             const float* __restrict__ tss_in,
                             const float* __restrict__ bz_in,
                             float* __restrict__ coef,
                             float* __restrict__ out)
{
  const int l = threadIdx.x;  // 0..63
  const float* GX = ws + WS_GX;
  const float* GY = ws + WS_GY;
  float* AWZT = coef;               // 33 x 32
  float* APT  = coef + 33 * NL;     // 33 x 32 (+P_i identity folded)
  float* ACZT = coef + 66 * NL;     // 33 x 32 (+Cz_i identity folded)

  float rP[32], rW[32], rC[32];
#pragma unroll
  for (int i = 0; i < 32; ++i) rP[i] = GX[(1 + i) * GXW + 1 + l];
#pragma unroll
  for (int i = 0; i < 32; ++i) rW[i] = (l < 32) ? GX[(1 + i) * GXW + 33 + l] : 0.f;
#pragma unroll
  for (int i = 0; i < 32; ++i) rC[i] = GY[(1 + i) * GYS + 1 + l];
  float dS  = (l < 32) ? GX[DIAG + l] : 0.f;  // ||Wz_l||^2
  float u0l = (l < 32) ? u_in[l]   : 0.f;
  float t0l = (l < 32) ? tss_in[l] : 0.f;
  float b0l = (l < 32) ? bz_in[l]  : 0.f;

  double q = (double)GX[0];                       // ||xr||^2
  double r = (double)GY[0];                       // ||yr||^2
  double pj = (l < 32) ? (double)GX[1 + l]  : 0.0;
  double wj = (l < 32) ? (double)GX[33 + l] : 0.0;
  double ej = (l < 32) ? (double)GY[1 + l]  : 0.0;
  double cx = (l == 0) ? 1.0 : 0.0;
  double cy = (l == 0) ? 1.0 : 0.0;

#pragma unroll
  for (int i = 0; i < NL; ++i) {
    double a  = __shfl(wj, i, 64);
    double g  = __shfl(ej, i, 64);
    double pi = __shfl(pj, i, 64);
    double s  = (double)__shfl(dS, i, 64);
    double h  = (double)__shfl(rC[i], i, 64);      // GY diag (1+i,1+i)
    double Pd = (double)__shfl(rP[i], i, 64);      // GX diag (1+i,1+i)
    double u0   = (double)__shfl(u0l, i, 64);
    double tss0 = (double)__shfl(t0l, i, 64);
    double bz0  = (double)__shfl(b0l, i, 64);

    double ui = u0, u1 = 0.0, tz = 0.0, tss_ = 0.0, t = 0.0, ncz = 1.0;
#pragma unroll
    for (int pass = 0; pass < 2; ++pass) {
      double num = a + ui * q;
      double den = sqrt(s + 2.0 * ui * a + ui * ui * q) + 1e-7;
      tz = num / den;
      tss_ = tss0 + tz * tz;
      t = tz / sqrt(tss_);
      double ncz2 = h + 2.0 * t * g + t * t * r;
      ncz = sqrt(ncz2);
      ui = (g + t * r) / ncz;
      if (pass == 0) u1 = ui;
    }
    double u2 = ui;
    double bz_new = bz0 + u2 * tz;
    double bb = bz_new / sqrt(tss_);
    double phi = 1.0 - t * t;            // xr' = phi*xr - t*P_i
    double gam = bb * t / ncz;           // yr' = psi*yr - gam*Cz_i
    double psi = 1.0 - gam * t;

    if (l == 0) {
      out[OUT_U + i]   = (float)u2;
      out[OUT_TSS + i] = (float)tss_;
      out[OUT_BZ + i]  = (float)bz_new;
    }
    if (l < 33) {
      AWZT[l * 32 + i] = (float)(u1 * cx);
      APT [l * 32 + i] = (float)(t  * cx) + ((l == 1 + i) ? 1.0f : 0.0f);
      ACZT[l * 32 + i] = (float)(t  * cy) + ((l == 1 + i) ? 1.0f : 0.0f);
    }
    q = phi * phi * q - 2.0 * phi * t * pi + t * t * Pd;
    r = psi * psi * r - 2.0 * psi * gam * g + gam * gam * h;
    cx *= phi; if (l == 1 + i) cx -= t;
    cy *= psi; if (l == 1 + i) cy -= gam;
    if (l < 32) {
      pj = phi * pj - t * (double)rP[i];
      wj = phi * wj - t * (double)rW[i];
      ej = psi * ej - gam * (double)rC[i];
    }
  }
}

// j-outer, 64 resident f32 accumulators per thread: B_j loaded once, consumed.
__global__ __launch_bounds__(256) void out_kernel(
    const float* __restrict__ x, const float* __restrict__ y,
    const float* __restrict__ mux, const float* __restrict__ muy,
    const float* __restrict__ Wz, const float* __restrict__ Cz,
    const float* __restrict__ P, const int* __restrict__ np,
    const float* __restrict__ coef, float* __restrict__ out)
{
  const int b = blockIdx.x, tid = threadIdx.x;
  const float n1 = (float)(np[0] + 1);
  const float inv = 1.0f / (n1 + 1.0f);
  const float* AWZT = coef;
  const float* APT  = coef + 33 * NL;
  const float* ACZT = coef + 66 * NL;

  if (b < 1024) {
    const int k = b * 256 + tid;
    float xv = x[k], mv = mux[k];
    float mn = (mv * n1 + xv) * inv;
    out[OUT_MU_X + k] = mn;
    float accW[32], accP[32];
#pragma unroll
    for (int i = 0; i < 32; ++i) accW[i] = Wz[(size_t)i * NF + k];
#pragma unroll
    for (int i = 0; i < 32; ++i) accP[i] = 0.f;
    {
      float B0 = xv - mn;
#pragma unroll
      for (int i = 0; i < 32; ++i) {
        accW[i] += AWZT[i] * B0;
        accP[i] += APT[i] * B0;
      }
    }
#pragma unroll 4
    for (int j = 1; j < 33; ++j) {
      float Bj = P[(size_t)(j - 1) * NF + k];
      const float* cw = AWZT + j * 32;
      const float* cp = APT + j * 32;
#pragma unroll
      for (int i = 0; i < 32; ++i) {
        accW[i] += cw[i] * Bj;
        accP[i] += cp[i] * Bj;
      }
    }
#pragma unroll
    for (int i = 0; i < 32; ++i) out[OUT_WZ + (size_t)i * NF + k] = accW[i];
#pragma unroll
    for (int i = 0; i < 32; ++i) out[OUT_P + (size_t)i * NF + k] = accP[i];
  } else {
    const int k = (b - 1024) * 256 + tid;
    float yv = y[k], mv = muy[k];
    float mn = (mv * n1 + yv) * inv;
    out[OUT_MU_Y + k] = mn;
    float accC[32];
#pragma unroll
    for (int i = 0; i < 32; ++i) accC[i] = 0.f;
    {
      float B0 = yv - mn;
#pragma unroll
      for (int i = 0; i < 32; ++i) accC[i] += ACZT[i] * B0;
    }
#pragma unroll 4
    for (int j = 1; j < 33; ++j) {
      float Bj = Cz[(size_t)(j - 1) * NT + k];
      const float* cc = ACZT + j * 32;
#pragma unroll
      for (int i = 0; i < 32; ++i) accC[i] += cc[i] * Bj;
    }
#pragma unroll
    for (int i = 0; i < 32; ++i) out[OUT_CZ + (size_t)i * NT + k] = accC[i];
  }
}

extern "C" void kernel_launch(void* const* d_in, const int* in_sizes, int n_in,
                              void* d_out, int out_size, void* d_ws, size_t ws_size,
                              hipStream_t stream) {
  const float* x   = (const float*)d_in[0];
  const float* y   = (const float*)d_in[1];
  const float* mux = (const float*)d_in[2];
  const float* muy = (const float*)d_in[3];
  const float* u   = (const float*)d_in[4];
  const float* Wz  = (const float*)d_in[5];
  const float* Cz  = (const float*)d_in[6];
  const float* tss = (const float*)d_in[7];
  const float* bz  = (const float*)d_in[8];
  const float* P   = (const float*)d_in[9];
  const int*   n   = (const int*)d_in[10];
  float* ws  = (float*)d_ws;
  float* out = (float*)d_out;

  // GY (atomics) and GX (atomic-reduced) both need zeroing; adjacent regions
  hipMemsetAsync(ws + WS_GY, 0, (size_t)(GYS * GYS + PBE) * sizeof(float), stream);
  gram_kernel<<<NBX + 32, 320, 0, stream>>>(x, y, mux, muy, Wz, Cz, P, n, ws);
  reduce_kernel<<<72, 256, 0, stream>>>(ws);
  solve_kernel<<<1, 64, 0, stream>>>(ws, u, tss, bz, ws + WS_COEF, out);
  out_kernel<<<1024 + 32, 256, 0, stream>>>(x, y, mux, muy, Wz, Cz, P, n, ws + WS_COEF, out);
}

// Round 2
// 244.816 us; speedup vs baseline: 1.0879x; 1.0876x over previous
//
#include <hip/hip_runtime.h>

// IPLS partial_fit (n > BURN_IN). Gram-reformulated.
// R7: (a) solve_kernel critical chain rewritten: every f64 sqrt/div pair ->
// v_rsq_f64 + 1 Newton (3e-14 rel), eps folded as tz=num*rs*(1-eps*rs).
// Was 58.9us serial-latency (VALUBusy 0.02%, 1 wave); chain ~7x shorter.
// (b) reduce_kernel eliminated: gram x-side blocks atomicAdd their 33x65(+diag)
// partials straight into GX (y-side already did this into GY). Saves a launch,
// the 4.7MB partial round-trip, and shrinks ws to 14KB.
// Gram itself unchanged from R6 (bf16-split MFMA SYRK, 2^-17 rel).

#define NF 262144
#define NT 8192
#define NL 32
#define GYS 36
#define LDSW 260       // y-side row stride (floats): 256 + 4 pad

#define NBX 512        // x-side K-slice blocks
#define KS  512        // K elems per block
#define CHK 128        // K elems per chunk (LDS resident)
#define NCHK (KS/CHK)  // 4
#define GXW 68         // Gram row stride (cols 0..64 used)
#define PBE 2276       // GX region: 33*68 + 32 diag
#define DIAG 2244      // 33*68

#define WS_GY   0
#define WS_GX   (GYS*GYS)            // 1296
#define WS_COEF (WS_GX + PBE)        // 3572 (+3168 -> 6740 floats, 27KB)

#define OUT_MU_X 0
#define OUT_MU_Y 262144
#define OUT_U    270336
#define OUT_WZ   270368
#define OUT_CZ   8658976
#define OUT_TSS  8921120
#define OUT_BZ   8921152
#define OUT_P    8921184

typedef __attribute__((ext_vector_type(8))) short bf16x8;
typedef __attribute__((ext_vector_type(4))) float f32x4;

__device__ __forceinline__ float4 ld4(const float* p) { return *(const float4*)p; }

__device__ __forceinline__ unsigned int f2bf_rne(float f) {
  unsigned int t = __float_as_uint(f);
  t += 0x7FFFu + ((t >> 16) & 1u);
  return t >> 16;
}

// f64 rsqrt: v_rsq_f64 seed (~2^-23) + one Newton step -> ~3e-14 relative.
__device__ __forceinline__ double rsq64(double x) {
  double r = __builtin_amdgcn_rsq(x);
  r = r * (1.5 - 0.5 * x * r * r);
  return r;
}

__global__ __launch_bounds__(320) void gram_kernel(
    const float* __restrict__ x, const float* __restrict__ y,
    const float* __restrict__ mux, const float* __restrict__ muy,
    const float* __restrict__ Wz, const float* __restrict__ Cz,
    const float* __restrict__ P, const int* __restrict__ np,
    float* __restrict__ ws)
{
  __shared__ __align__(16) char smem[80 * CHK * 4 + 128];  // hi+lo planes + diag
  const int tid = threadIdx.x;
  const int b = blockIdx.x;
  const float n1 = (float)(np[0] + 1);
  const float cmu = n1 / (n1 + 1.0f);   // xc = cmu*(x - mu_old)

  if (b < NBX) {
    // ---- x-side: bf16-split MFMA SYRK slice ----
    char* hB = smem;                        // hi plane: [80][128] bf16
    char* lB = smem + 80 * CHK * 2;         // lo plane
    float* sdiag = (float*)(smem + 80 * CHK * 4);

    if (tid < 32) sdiag[tid] = 0.f;
    {  // zero pad rows 65..79 (both planes), once; stays zero across chunks
      unsigned int* hz = (unsigned int*)hB;
      unsigned int* lz = (unsigned int*)lB;
      for (int i = tid; i < 960; i += 320) { hz[65 * 64 + i] = 0u; lz[65 * 64 + i] = 0u; }
    }

    f32x4 acc0 = {0.f, 0.f, 0.f, 0.f};
    f32x4 acc1 = acc0, acc2 = acc0;
    const int lane = tid & 63;
    const int w = tid >> 6;            // wave = N-tile 0..4 (cols w*16..w*16+15)
    const int col16 = lane & 15;
    const int kgrp = lane >> 4;        // 0..3
    const int swz = (col16 & 7) << 4;  // (row&7)<<4; row%8 == col16%8 for all frags

    for (int c = 0; c < NCHK; ++c) {
      __syncthreads();                 // prev compute done before overwrite
      const int kb = b * KS + c * CHK;
      // stage: 65 rows x 32 float4 = 2080 loads; convert fp32 -> bf16 hi/lo
#pragma unroll
      for (int it = 0; it < 7; ++it) {
        int idx = tid + it * 320;
        if (idx < 2080) {
          int row = idx >> 5;
          int c4 = idx & 31;
          int k = kb + c4 * 4;
          float4 v;
          if (row == 0) {
            float4 xv = ld4(x + k), mv = ld4(mux + k);
            v.x = cmu * (xv.x - mv.x); v.y = cmu * (xv.y - mv.y);
            v.z = cmu * (xv.z - mv.z); v.w = cmu * (xv.w - mv.w);
          } else if (row < 33) {
            v = ld4(P + (size_t)(row - 1) * NF + k);
          } else {
            v = ld4(Wz + (size_t)(row - 33) * NF + k);
            atomicAdd(&sdiag[row - 33], v.x * v.x + v.y * v.y + v.z * v.z + v.w * v.w);
          }
          unsigned int b0 = __float_as_uint(v.x), b1 = __float_as_uint(v.y);
          unsigned int b2 = __float_as_uint(v.z), b3 = __float_as_uint(v.w);
          float h0 = __uint_as_float(b0 & 0xFFFF0000u);
          float h1 = __uint_as_float(b1 & 0xFFFF0000u);
          float h2 = __uint_as_float(b2 & 0xFFFF0000u);
          float h3 = __uint_as_float(b3 & 0xFFFF0000u);
          uint2 hw, lw;
          hw.x = (b0 >> 16) | ((b1 >> 16) << 16);
          hw.y = (b2 >> 16) | ((b3 >> 16) << 16);
          lw.x = f2bf_rne(v.x - h0) | (f2bf_rne(v.y - h1) << 16);
          lw.y = f2bf_rne(v.z - h2) | (f2bf_rne(v.w - h3) << 16);
          int off = ((row << 8) + (c4 << 3)) ^ ((row & 7) << 4);
          *(uint2*)(hB + off) = hw;
          *(uint2*)(lB + off) = lw;
        }
      }
      __syncthreads();
      // compute: 4 K-steps of 32; per step: 8 ds_read_b128 + 12 MFMA
#pragma unroll
      for (int s = 0; s < 4; ++s) {
        const int kbyte = s * 64 + kgrp * 16;
        const int oa = ((col16 << 8) + kbyte) ^ swz;   // M-tile 0 (rows 0..15)
        const int ob = oa + (w << 12);                 // N-tile w
        bf16x8 bh = *(const bf16x8*)(hB + ob);
        bf16x8 bl = *(const bf16x8*)(lB + ob);
        bf16x8 a0h = *(const bf16x8*)(hB + oa);
        bf16x8 a0l = *(const bf16x8*)(lB + oa);
        acc0 = __builtin_amdgcn_mfma_f32_16x16x32_bf16(a0h, bh, acc0, 0, 0, 0);
        acc0 = __builtin_amdgcn_mfma_f32_16x16x32_bf16(a0h, bl, acc0, 0, 0, 0);
        acc0 = __builtin_amdgcn_mfma_f32_16x16x32_bf16(a0l, bh, acc0, 0, 0, 0);
        acc0 = __builtin_amdgcn_mfma_f32_16x16x32_bf16(a0l, bl, acc0, 0, 0, 0);
        bf16x8 a1h = *(const bf16x8*)(hB + oa + 4096);  // rows 16..31
        bf16x8 a1l = *(const bf16x8*)(lB + oa + 4096);
        acc1 = __builtin_amdgcn_mfma_f32_16x16x32_bf16(a1h, bh, acc1, 0, 0, 0);
        acc1 = __builtin_amdgcn_mfma_f32_16x16x32_bf16(a1h, bl, acc1, 0, 0, 0);
        acc1 = __builtin_amdgcn_mfma_f32_16x16x32_bf16(a1l, bh, acc1, 0, 0, 0);
        acc1 = __builtin_amdgcn_mfma_f32_16x16x32_bf16(a1l, bl, acc1, 0, 0, 0);
        bf16x8 a2h = *(const bf16x8*)(hB + oa + 8192);  // rows 32..47 (row 32 = P31)
        bf16x8 a2l = *(const bf16x8*)(lB + oa + 8192);
        acc2 = __builtin_amdgcn_mfma_f32_16x16x32_bf16(a2h, bh, acc2, 0, 0, 0);
        acc2 = __builtin_amdgcn_mfma_f32_16x16x32_bf16(a2h, bl, acc2, 0, 0, 0);
        acc2 = __builtin_amdgcn_mfma_f32_16x16x32_bf16(a2l, bh, acc2, 0, 0, 0);
        acc2 = __builtin_amdgcn_mfma_f32_16x16x32_bf16(a2l, bl, acc2, 0, 0, 0);
      }
    }
    // accumulate partial straight into GX (device atomics; ~2.2K addrs, 512 ways)
    float* GX = ws + WS_GX;
    const int vcol = w * 16 + col16;
    if (vcol < 65) {
#pragma unroll
      for (int r2 = 0; r2 < 4; ++r2) {
        int u = kgrp * 4 + r2;
        atomicAdd(&GX[u * GXW + vcol], acc0[r2]);           // rows 0..15
        atomicAdd(&GX[(16 + u) * GXW + vcol], acc1[r2]);    // rows 16..31
      }
      if (kgrp == 0) atomicAdd(&GX[32 * GXW + vcol], acc2[0]);  // row 32 only
    }
    if (tid < 32) atomicAdd(&GX[DIAG + tid], sdiag[tid]);   // drained by last barrier
  } else {
    // ---- y-side: unchanged (36 rows [yc, Cz_0..31, zeros]) ----
    float* lds = (float*)smem;   // 36*260*4 = 37.4KB <= 41KB alias
    float* GY = ws + WS_GY;
    const int yb = b - NBX;
    int gu = 0, gv = 0; bool active = (tid < 45);
    if (active) {
      int pp = tid;
      for (int g = 0; g < 9; ++g) {
        int cnt = 9 - g;
        if (pp < cnt) { gu = g; gv = g + pp; break; }
        pp -= cnt;
      }
    }
    float acc[16];
#pragma unroll
    for (int i = 0; i < 16; ++i) acc[i] = 0.f;
    const int wb = yb * 256;
    for (int it = 0; it < 8; ++it) {
      int idx = tid + it * 320;
      if (idx < 2304) {
        int row = idx >> 6;
        int c4 = idx & 63;
        int k = wb + c4 * 4;
        float4 v;
        if (row == 0) {
          float4 yv = ld4(y + k), mv = ld4(muy + k);
          v.x = cmu * (yv.x - mv.x); v.y = cmu * (yv.y - mv.y);
          v.z = cmu * (yv.z - mv.z); v.w = cmu * (yv.w - mv.w);
        } else if (row < 33) {
          v = ld4(Cz + (size_t)(row - 1) * NT + k);
        } else {
          v = make_float4(0.f, 0.f, 0.f, 0.f);
        }
        *(float4*)&lds[row * LDSW + c4 * 4] = v;
      }
    }
    __syncthreads();
    if (active) {
      const int ub = 4 * gu * LDSW, vb = 4 * gv * LDSW;
      for (int c = 0; c < 64; ++c) {
        float4 av[4], bv[4];
#pragma unroll
        for (int r = 0; r < 4; ++r) av[r] = *(const float4*)&lds[ub + r * LDSW + c * 4];
#pragma unroll
        for (int s = 0; s < 4; ++s) bv[s] = *(const float4*)&lds[vb + s * LDSW + c * 4];
#pragma unroll
        for (int r = 0; r < 4; ++r)
#pragma unroll
          for (int s = 0; s < 4; ++s)
            acc[r * 4 + s] += av[r].x * bv[s].x + av[r].y * bv[s].y +
                              av[r].z * bv[s].z + av[r].w * bv[s].w;
      }
#pragma unroll
      for (int r = 0; r < 4; ++r)
#pragma unroll
        for (int s = 0; s < 4; ++s) {
          int u = 4 * gu + r, v = 4 * gv + s;
          if (u < 33 && v < 33) {
            float val = acc[r * 4 + s];
            atomicAdd(&GY[u * GYS + v], val);
            if (gu != gv) atomicAdd(&GY[v * GYS + u], val);
          }
        }
    }
  }
}

// One wave: f64 scalar recurrences for all 32 components; Gram rows preloaded
// into registers; i-loop fully unrolled (compile-time __shfl indices).
// Critical chain uses rsq64 (v_rsq_f64 + 1 Newton) -- no f64 sqrt/div.
__global__ void solve_kernel(const float* __restrict__ ws,
                             const float* __restrict__ u_in,
                             const float* __restrict__ tss_in,
                             const float* __restrict__ bz_in,
                             float* __restrict__ coef,
                             float* __restrict__ out)
{
  const int l = threadIdx.x;  // 0..63
  const float* GX = ws + WS_GX;
  const float* GY = ws + WS_GY;
  float* AWZT = coef;               // 33 x 32
  float* APT  = coef + 33 * NL;     // 33 x 32 (+P_i identity folded)
  float* ACZT = coef + 66 * NL;     // 33 x 32 (+Cz_i identity folded)

  float rP[32], rW[32], rC[32];
#pragma unroll
  for (int i = 0; i < 32; ++i) rP[i] = GX[(1 + i) * GXW + 1 + l];
#pragma unroll
  for (int i = 0; i < 32; ++i) rW[i] = (l < 32) ? GX[(1 + i) * GXW + 33 + l] : 0.f;
#pragma unroll
  for (int i = 0; i < 32; ++i) rC[i] = GY[(1 + i) * GYS + 1 + l];
  float dS  = (l < 32) ? GX[DIAG + l] : 0.f;  // ||Wz_l||^2
  float u0l = (l < 32) ? u_in[l]   : 0.f;
  float t0l = (l < 32) ? tss_in[l] : 0.f;
  float b0l = (l < 32) ? bz_in[l]  : 0.f;

  double q = (double)GX[0];                       // ||xr||^2
  double r = (double)GY[0];                       // ||yr||^2
  double pj = (l < 32) ? (double)GX[1 + l]  : 0.0;
  double wj = (l < 32) ? (double)GX[33 + l] : 0.0;
  double ej = (l < 32) ? (double)GY[1 + l]  : 0.0;
  double cx = (l == 0) ? 1.0 : 0.0;
  double cy = (l == 0) ? 1.0 : 0.0;

#pragma unroll
  for (int i = 0; i < NL; ++i) {
    double a  = __shfl(wj, i, 64);
    double g  = __shfl(ej, i, 64);
    double pi = __shfl(pj, i, 64);
    double s  = (double)__shfl(dS, i, 64);
    double h  = (double)__shfl(rC[i], i, 64);      // GY diag (1+i,1+i)
    double Pd = (double)__shfl(rP[i], i, 64);      // GX diag (1+i,1+i)
    double u0   = (double)__shfl(u0l, i, 64);
    double tss0 = (double)__shfl(t0l, i, 64);
    double bz0  = (double)__shfl(b0l, i, 64);

    double ui = u0, u1 = 0.0, tz = 0.0, tss_ = 0.0, t = 0.0;
    double rt = 0.0, rn = 0.0;
#pragma unroll
    for (int pass = 0; pass < 2; ++pass) {
      double num = a + ui * q;
      double s2  = s + 2.0 * ui * a + ui * ui * q;
      double rs  = rsq64(s2);
      tz = num * rs * (1.0 - 1e-7 * rs);     // num/(sqrt(s2)+eps) to ~2e-10
      tss_ = tss0 + tz * tz;
      rt = rsq64(tss_);
      t  = tz * rt;
      double ncz2 = h + 2.0 * t * g + t * t * r;
      rn = rsq64(ncz2);
      ui = (g + t * r) * rn;
      if (pass == 0) u1 = ui;
    }
    double u2 = ui;
    double bz_new = bz0 + u2 * tz;
    double bb = bz_new * rt;             // bz_new / sqrt(tss_)
    double phi = 1.0 - t * t;            // xr' = phi*xr - t*P_i
    double gam = bb * t * rn;            // yr' = psi*yr - gam*Cz_i
    double psi = 1.0 - gam * t;

    if (l == 0) {
      out[OUT_U + i]   = (float)u2;
      out[OUT_TSS + i] = (float)tss_;
      out[OUT_BZ + i]  = (float)bz_new;
    }
    if (l < 33) {
      AWZT[l * 32 + i] = (float)(u1 * cx);
      APT [l * 32 + i] = (float)(t  * cx) + ((l == 1 + i) ? 1.0f : 0.0f);
      ACZT[l * 32 + i] = (float)(t  * cy) + ((l == 1 + i) ? 1.0f : 0.0f);
    }
    q = phi * phi * q - 2.0 * phi * t * pi + t * t * Pd;
    r = psi * psi * r - 2.0 * psi * gam * g + gam * gam * h;
    cx *= phi; if (l == 1 + i) cx -= t;
    cy *= psi; if (l == 1 + i) cy -= gam;
    if (l < 32) {
      pj = phi * pj - t * (double)rP[i];
      wj = phi * wj - t * (double)rW[i];
      ej = psi * ej - gam * (double)rC[i];
    }
  }
}

// j-outer, 64 resident f32 accumulators per thread: B_j loaded once, consumed.
__global__ __launch_bounds__(256) void out_kernel(
    const float* __restrict__ x, const float* __restrict__ y,
    const float* __restrict__ mux, const float* __restrict__ muy,
    const float* __restrict__ Wz, const float* __restrict__ Cz,
    const float* __restrict__ P, const int* __restrict__ np,
    const float* __restrict__ coef, float* __restrict__ out)
{
  const int b = blockIdx.x, tid = threadIdx.x;
  const float n1 = (float)(np[0] + 1);
  const float inv = 1.0f / (n1 + 1.0f);
  const float* AWZT = coef;
  const float* APT  = coef + 33 * NL;
  const float* ACZT = coef + 66 * NL;

  if (b < 1024) {
    const int k = b * 256 + tid;
    float xv = x[k], mv = mux[k];
    float mn = (mv * n1 + xv) * inv;
    out[OUT_MU_X + k] = mn;
    float accW[32], accP[32];
#pragma unroll
    for (int i = 0; i < 32; ++i) accW[i] = Wz[(size_t)i * NF + k];
#pragma unroll
    for (int i = 0; i < 32; ++i) accP[i] = 0.f;
    {
      float B0 = xv - mn;
#pragma unroll
      for (int i = 0; i < 32; ++i) {
        accW[i] += AWZT[i] * B0;
        accP[i] += APT[i] * B0;
      }
    }
#pragma unroll 4
    for (int j = 1; j < 33; ++j) {
      float Bj = P[(size_t)(j - 1) * NF + k];
      const float* cw = AWZT + j * 32;
      const float* cp = APT + j * 32;
#pragma unroll
      for (int i = 0; i < 32; ++i) {
        accW[i] += cw[i] * Bj;
        accP[i] += cp[i] * Bj;
      }
    }
#pragma unroll
    for (int i = 0; i < 32; ++i) out[OUT_WZ + (size_t)i * NF + k] = accW[i];
#pragma unroll
    for (int i = 0; i < 32; ++i) out[OUT_P + (size_t)i * NF + k] = accP[i];
  } else {
    const int k = (b - 1024) * 256 + tid;
    float yv = y[k], mv = muy[k];
    float mn = (mv * n1 + yv) * inv;
    out[OUT_MU_Y + k] = mn;
    float accC[32];
#pragma unroll
    for (int i = 0; i < 32; ++i) accC[i] = 0.f;
    {
      float B0 = yv - mn;
#pragma unroll
      for (int i = 0; i < 32; ++i) accC[i] += ACZT[i] * B0;
    }
#pragma unroll 4
    for (int j = 1; j < 33; ++j) {
      float Bj = Cz[(size_t)(j - 1) * NT + k];
      const float* cc = ACZT + j * 32;
#pragma unroll
      for (int i = 0; i < 32; ++i) accC[i] += cc[i] * Bj;
    }
#pragma unroll
    for (int i = 0; i < 32; ++i) out[OUT_CZ + (size_t)i * NT + k] = accC[i];
  }
}

extern "C" void kernel_launch(void* const* d_in, const int* in_sizes, int n_in,
                              void* d_out, int out_size, void* d_ws, size_t ws_size,
                              hipStream_t stream) {
  const float* x   = (const float*)d_in[0];
  const float* y   = (const float*)d_in[1];
  const float* mux = (const float*)d_in[2];
  const float* muy = (const float*)d_in[3];
  const float* u   = (const float*)d_in[4];
  const float* Wz  = (const float*)d_in[5];
  const float* Cz  = (const float*)d_in[6];
  const float* tss = (const float*)d_in[7];
  const float* bz  = (const float*)d_in[8];
  const float* P   = (const float*)d_in[9];
  const int*   n   = (const int*)d_in[10];
  float* ws  = (float*)d_ws;
  float* out = (float*)d_out;

  // GY and GX are both atomically accumulated -> zero both (adjacent)
  hipMemsetAsync(ws + WS_GY, 0, (size_t)(GYS * GYS + PBE) * sizeof(float), stream);
  gram_kernel<<<NBX + 32, 320, 0, stream>>>(x, y, mux, muy, Wz, Cz, P, n, ws);
  solve_kernel<<<1, 64, 0, stream>>>(ws, u, tss, bz, ws + WS_COEF, out);
  out_kernel<<<1024 + 32, 256, 0, stream>>>(x, y, mux, muy, Wz, Cz, P, n, ws + WS_COEF, out);
}

// Round 3
// 233.094 us; speedup vs baseline: 1.1426x; 1.0503x over previous
//
#include <hip/hip_runtime.h>

// IPLS partial_fit (n > BURN_IN). Gram-reformulated.
// R8: (a) GX accumulation reverted to per-block partial STORES + reduce kernel
// (R7's 1.1M same-address global atomics cost ~17us in tail/drain serialization).
// (b) gram staging restructured T14-style: all global loads of chunk c+1 are
// issued into registers BEFORE the MFMA compute of chunk c (one latency
// exposure per chunk instead of 7 serial load->convert round trips).
// (c) y-side loads batched the same way.
// solve keeps R7's rsq64 chain (v_rsq_f64 + 1 Newton). out_kernel unchanged.

#define NF 262144
#define NT 8192
#define NL 32
#define GYS 36
#define LDSW 260       // y-side row stride (floats): 256 + 4 pad

#define NBX 512        // x-side K-slice blocks
#define KS  512        // K elems per block
#define CHK 128        // K elems per chunk (LDS resident)
#define NCHK (KS/CHK)  // 4
#define GXW 68         // Gram row stride (cols 0..64 used)
#define PBE 2276       // per-block partial: 33*68 + 32 diag
#define DIAG 2244      // 33*68

#define WS_PART 0
#define WS_GY   (NBX*PBE)            // 1165312
#define WS_GX   (WS_GY + GYS*GYS)    // 1166608
#define WS_COEF (WS_GX + PBE)        // 1168884 (+3168 -> 1172052 floats, 4.7MB)

#define OUT_MU_X 0
#define OUT_MU_Y 262144
#define OUT_U    270336
#define OUT_WZ   270368
#define OUT_CZ   8658976
#define OUT_TSS  8921120
#define OUT_BZ   8921152
#define OUT_P    8921184

typedef __attribute__((ext_vector_type(8))) short bf16x8;
typedef __attribute__((ext_vector_type(4))) float f32x4;

__device__ __forceinline__ float4 ld4(const float* p) { return *(const float4*)p; }

__device__ __forceinline__ unsigned int f2bf_rne(float f) {
  unsigned int t = __float_as_uint(f);
  t += 0x7FFFu + ((t >> 16) & 1u);
  return t >> 16;
}

// f64 rsqrt: v_rsq_f64 seed (~2^-23) + one Newton step -> ~3e-14 relative.
__device__ __forceinline__ double rsq64(double x) {
  double r = __builtin_amdgcn_rsq(x);
  r = r * (1.5 - 0.5 * x * r * r);
  return r;
}

__global__ __launch_bounds__(320) void gram_kernel(
    const float* __restrict__ x, const float* __restrict__ y,
    const float* __restrict__ mux, const float* __restrict__ muy,
    const float* __restrict__ Wz, const float* __restrict__ Cz,
    const float* __restrict__ P, const int* __restrict__ np,
    float* __restrict__ ws)
{
  __shared__ __align__(16) char smem[80 * CHK * 4 + 128];  // hi+lo planes + diag
  const int tid = threadIdx.x;
  const int b = blockIdx.x;
  const float n1 = (float)(np[0] + 1);
  const float cmu = n1 / (n1 + 1.0f);   // xc = cmu*(x - mu_old)

  if (b < NBX) {
    // ---- x-side: bf16-split MFMA SYRK slice, register-prefetched staging ----
    char* hB = smem;                        // hi plane: [80][128] bf16
    char* lB = smem + 80 * CHK * 2;         // lo plane
    float* sdiag = (float*)(smem + 80 * CHK * 4);

    if (tid < 32) sdiag[tid] = 0.f;
    {  // zero pad rows 65..79 (both planes), once; stays zero across chunks
      unsigned int* hz = (unsigned int*)hB;
      unsigned int* lz = (unsigned int*)lB;
      for (int i = tid; i < 960; i += 320) { hz[65 * 64 + i] = 0u; lz[65 * 64 + i] = 0u; }
    }

    f32x4 acc0 = {0.f, 0.f, 0.f, 0.f};
    f32x4 acc1 = acc0, acc2 = acc0;
    const int lane = tid & 63;
    const int w = tid >> 6;            // wave = N-tile 0..4 (cols w*16..w*16+15)
    const int col16 = lane & 15;
    const int kgrp = lane >> 4;        // 0..3
    const int swz = (col16 & 7) << 4;  // (row&7)<<4; row%8 == col16%8 for all frags

    float4 v[7]; float4 vm0;           // staged loads for next chunk

    // issue all 7 loads for chunk c (fire-and-forget; consumed by convert)
    auto issue_loads = [&](int c) {
      const int kb = b * KS + c * CHK;
#pragma unroll
      for (int it = 0; it < 7; ++it) {
        int idx = tid + it * 320;
        if (idx < 2080) {
          int row = idx >> 5;
          int c4 = idx & 31;
          int k = kb + c4 * 4;
          const float* bp = (row == 0) ? (x + k)
                          : (row < 33) ? (P + (size_t)(row - 1) * NF + k)
                                       : (Wz + (size_t)(row - 33) * NF + k);
          v[it] = ld4(bp);
          if (it == 0 && row == 0) vm0 = ld4(mux + k);
        }
      }
    };

    // convert staged regs -> bf16 hi/lo planes in LDS (+ Wz diag atomics)
    auto convert_write = [&]() {
#pragma unroll
      for (int it = 0; it < 7; ++it) {
        int idx = tid + it * 320;
        if (idx < 2080) {
          int row = idx >> 5;
          int c4 = idx & 31;
          float4 t4 = v[it];
          if (it == 0 && row == 0) {
            t4.x = cmu * (t4.x - vm0.x); t4.y = cmu * (t4.y - vm0.y);
            t4.z = cmu * (t4.z - vm0.z); t4.w = cmu * (t4.w - vm0.w);
          }
          if (row >= 33)
            atomicAdd(&sdiag[row - 33],
                      t4.x * t4.x + t4.y * t4.y + t4.z * t4.z + t4.w * t4.w);
          unsigned int b0 = __float_as_uint(t4.x), b1 = __float_as_uint(t4.y);
          unsigned int b2 = __float_as_uint(t4.z), b3 = __float_as_uint(t4.w);
          float h0 = __uint_as_float(b0 & 0xFFFF0000u);
          float h1 = __uint_as_float(b1 & 0xFFFF0000u);
          float h2 = __uint_as_float(b2 & 0xFFFF0000u);
          float h3 = __uint_as_float(b3 & 0xFFFF0000u);
          uint2 hw, lw;
          hw.x = (b0 >> 16) | ((b1 >> 16) << 16);
          hw.y = (b2 >> 16) | ((b3 >> 16) << 16);
          lw.x = f2bf_rne(t4.x - h0) | (f2bf_rne(t4.y - h1) << 16);
          lw.y = f2bf_rne(t4.z - h2) | (f2bf_rne(t4.w - h3) << 16);
          int off = ((row << 8) + (c4 << 3)) ^ ((row & 7) << 4);
          *(uint2*)(hB + off) = hw;
          *(uint2*)(lB + off) = lw;
        }
      }
    };

    issue_loads(0);
    for (int c = 0; c < NCHK; ++c) {
      __syncthreads();                 // prev compute done before overwrite
      convert_write();
      __syncthreads();
      if (c + 1 < NCHK) issue_loads(c + 1);   // latency hidden under compute
      // compute: 4 K-steps of 32; per step: 8 ds_read_b128 + 12 MFMA
#pragma unroll
      for (int s = 0; s < 4; ++s) {
        const int kbyte = s * 64 + kgrp * 16;
        const int oa = ((col16 << 8) + kbyte) ^ swz;   // M-tile 0 (rows 0..15)
        const int ob = oa + (w << 12);                 // N-tile w
        bf16x8 bh = *(const bf16x8*)(hB + ob);
        bf16x8 bl = *(const bf16x8*)(lB + ob);
        bf16x8 a0h = *(const bf16x8*)(hB + oa);
        bf16x8 a0l = *(const bf16x8*)(lB + oa);
        acc0 = __builtin_amdgcn_mfma_f32_16x16x32_bf16(a0h, bh, acc0, 0, 0, 0);
        acc0 = __builtin_amdgcn_mfma_f32_16x16x32_bf16(a0h, bl, acc0, 0, 0, 0);
        acc0 = __builtin_amdgcn_mfma_f32_16x16x32_bf16(a0l, bh, acc0, 0, 0, 0);
        acc0 = __builtin_amdgcn_mfma_f32_16x16x32_bf16(a0l, bl, acc0, 0, 0, 0);
        bf16x8 a1h = *(const bf16x8*)(hB + oa + 4096);  // rows 16..31
        bf16x8 a1l = *(const bf16x8*)(lB + oa + 4096);
        acc1 = __builtin_amdgcn_mfma_f32_16x16x32_bf16(a1h, bh, acc1, 0, 0, 0);
        acc1 = __builtin_amdgcn_mfma_f32_16x16x32_bf16(a1h, bl, acc1, 0, 0, 0);
        acc1 = __builtin_amdgcn_mfma_f32_16x16x32_bf16(a1l, bh, acc1, 0, 0, 0);
        acc1 = __builtin_amdgcn_mfma_f32_16x16x32_bf16(a1l, bl, acc1, 0, 0, 0);
        bf16x8 a2h = *(const bf16x8*)(hB + oa + 8192);  // rows 32..47 (row 32 = P31)
        bf16x8 a2l = *(const bf16x8*)(lB + oa + 8192);
        acc2 = __builtin_amdgcn_mfma_f32_16x16x32_bf16(a2h, bh, acc2, 0, 0, 0);
        acc2 = __builtin_amdgcn_mfma_f32_16x16x32_bf16(a2h, bl, acc2, 0, 0, 0);
        acc2 = __builtin_amdgcn_mfma_f32_16x16x32_bf16(a2l, bh, acc2, 0, 0, 0);
        acc2 = __builtin_amdgcn_mfma_f32_16x16x32_bf16(a2l, bl, acc2, 0, 0, 0);
      }
    }
    // partial write: D layout col=lane&15, row=(lane>>4)*4+reg [m89]
    float* PB = ws + WS_PART + (size_t)b * PBE;
    const int vcol = w * 16 + col16;
    if (vcol < 65) {
#pragma unroll
      for (int r2 = 0; r2 < 4; ++r2) {
        int u = kgrp * 4 + r2;
        PB[u * GXW + vcol] = acc0[r2];              // rows 0..15
        PB[(16 + u) * GXW + vcol] = acc1[r2];       // rows 16..31
      }
      if (kgrp == 0) PB[32 * GXW + vcol] = acc2[0]; // row 32 only
    }
    if (tid < 32) PB[DIAG + tid] = sdiag[tid];      // atomics drained by last barrier
  } else {
    // ---- y-side: 36 rows [yc, Cz_0..31, zeros]; loads batched to regs ----
    float* lds = (float*)smem;   // 36*260*4 = 37.4KB <= 41KB alias
    float* GY = ws + WS_GY;
    const int yb = b - NBX;
    int gu = 0, gv = 0; bool active = (tid < 45);
    if (active) {
      int pp = tid;
      for (int g = 0; g < 9; ++g) {
        int cnt = 9 - g;
        if (pp < cnt) { gu = g; gv = g + pp; break; }
        pp -= cnt;
      }
    }
    float acc[16];
#pragma unroll
    for (int i = 0; i < 16; ++i) acc[i] = 0.f;
    const int wb = yb * 256;
    float4 vy[8]; float4 vmy;
#pragma unroll
    for (int it = 0; it < 8; ++it) {
      int idx = tid + it * 320;
      if (idx < 2304) {
        int row = idx >> 6;
        int c4 = idx & 63;
        int k = wb + c4 * 4;
        if (row == 0) {
          vy[it] = ld4(y + k);
          if (it == 0) vmy = ld4(muy + k);
        } else if (row < 33) {
          vy[it] = ld4(Cz + (size_t)(row - 1) * NT + k);
        } else {
          vy[it] = make_float4(0.f, 0.f, 0.f, 0.f);
        }
      }
    }
#pragma unroll
    for (int it = 0; it < 8; ++it) {
      int idx = tid + it * 320;
      if (idx < 2304) {
        int row = idx >> 6;
        int c4 = idx & 63;
        float4 t4 = vy[it];
        if (it == 0 && row == 0) {
          t4.x = cmu * (t4.x - vmy.x); t4.y = cmu * (t4.y - vmy.y);
          t4.z = cmu * (t4.z - vmy.z); t4.w = cmu * (t4.w - vmy.w);
        }
        *(float4*)&lds[row * LDSW + c4 * 4] = t4;
      }
    }
    __syncthreads();
    if (active) {
      const int ub = 4 * gu * LDSW, vb = 4 * gv * LDSW;
      for (int c = 0; c < 64; ++c) {
        float4 av[4], bv[4];
#pragma unroll
        for (int r = 0; r < 4; ++r) av[r] = *(const float4*)&lds[ub + r * LDSW + c * 4];
#pragma unroll
        for (int s = 0; s < 4; ++s) bv[s] = *(const float4*)&lds[vb + s * LDSW + c * 4];
#pragma unroll
        for (int r = 0; r < 4; ++r)
#pragma unroll
          for (int s = 0; s < 4; ++s)
            acc[r * 4 + s] += av[r].x * bv[s].x + av[r].y * bv[s].y +
                              av[r].z * bv[s].z + av[r].w * bv[s].w;
      }
#pragma unroll
      for (int r = 0; r < 4; ++r)
#pragma unroll
        for (int s = 0; s < 4; ++s) {
          int u = 4 * gu + r, v = 4 * gv + s;
          if (u < 33 && v < 33) {
            float val = acc[r * 4 + s];
            atomicAdd(&GY[u * GYS + v], val);
            if (gu != gv) atomicAdd(&GY[v * GYS + u], val);
          }
        }
    }
  }
}

// one-stage chunked reduce: 8 chunks x 64 blocks -> atomicAdd into GX (8/addr)
__global__ __launch_bounds__(256) void reduce_kernel(float* __restrict__ ws) {
  const int e = (blockIdx.x % 9) * 256 + threadIdx.x;
  const int c = blockIdx.x / 9;          // 0..7
  if (e < PBE) {
    const float* PB = ws + WS_PART + (size_t)(c * 64) * PBE + e;
    float s0 = 0.f, s1 = 0.f, s2 = 0.f, s3 = 0.f;
#pragma unroll
    for (int j = 0; j < 64; j += 4) {
      s0 += PB[(size_t)j * PBE];
      s1 += PB[(size_t)(j + 1) * PBE];
      s2 += PB[(size_t)(j + 2) * PBE];
      s3 += PB[(size_t)(j + 3) * PBE];
    }
    atomicAdd(ws + WS_GX + e, (s0 + s1) + (s2 + s3));
  }
}

// One wave: f64 scalar recurrences for all 32 components; Gram rows preloaded
// into registers; i-loop fully unrolled (compile-time __shfl indices).
// Critical chain uses rsq64 (v_rsq_f64 + 1 Newton) -- no f64 sqrt/div.
__global__ void solve_kernel(const float* __restrict__ ws,
                             const float* __restrict__ u_in,
                             const float* __restrict__ tss_in,
                             const float* __restrict__ bz_in,
                             float* __restrict__ coef,
                             float* __restrict__ out)
{
  const int l = threadIdx.x;  // 0..63
  const float* GX = ws + WS_GX;
  const float* GY = ws + WS_GY;
  float* AWZT = coef;               // 33 x 32
  float* APT  = coef + 33 * NL;     // 33 x 32 (+P_i identity folded)
  float* ACZT = coef + 66 * NL;     // 33 x 32 (+Cz_i identity folded)

  float rP[32], rW[32], rC[32];
#pragma unroll
  for (int i = 0; i < 32; ++i) rP[i] = GX[(1 + i) * GXW + 1 + l];
#pragma unroll
  for (int i = 0; i < 32; ++i) rW[i] = (l < 32) ? GX[(1 + i) * GXW + 33 + l] : 0.f;
#pragma unroll
  for (int i = 0; i < 32; ++i) rC[i] = GY[(1 + i) * GYS + 1 + l];
  float dS  = (l < 32) ? GX[DIAG + l] : 0.f;  // ||Wz_l||^2
  float u0l = (l < 32) ? u_in[l]   : 0.f;
  float t0l = (l < 32) ? tss_in[l] : 0.f;
  float b0l = (l < 32) ? bz_in[l]  : 0.f;

  double q = (double)GX[0];                       // ||xr||^2
  double r = (double)GY[0];                       // ||yr||^2
  double pj = (l < 32) ? (double)GX[1 + l]  : 0.0;
  double wj = (l < 32) ? (double)GX[33 + l] : 0.0;
  double ej = (l < 32) ? (double)GY[1 + l]  : 0.0;
  double cx = (l == 0) ? 1.0 : 0.0;
  double cy = (l == 0) ? 1.0 : 0.0;

#pragma unroll
  for (int i = 0; i < NL; ++i) {
    double a  = __shfl(wj, i, 64);
    double g  = __shfl(ej, i, 64);
    double pi = __shfl(pj, i, 64);
    double s  = (double)__shfl(dS, i, 64);
    double h  = (double)__shfl(rC[i], i, 64);      // GY diag (1+i,1+i)
    double Pd = (double)__shfl(rP[i], i, 64);      // GX diag (1+i,1+i)
    double u0   = (double)__shfl(u0l, i, 64);
    double tss0 = (double)__shfl(t0l, i, 64);
    double bz0  = (double)__shfl(b0l, i, 64);

    double ui = u0, u1 = 0.0, tz = 0.0, tss_ = 0.0, t = 0.0;
    double rt = 0.0, rn = 0.0;
#pragma unroll
    for (int pass = 0; pass < 2; ++pass) {
      double num = a + ui * q;
      double s2  = s + 2.0 * ui * a + ui * ui * q;
      double rs  = rsq64(s2);
      tz = num * rs * (1.0 - 1e-7 * rs);     // num/(sqrt(s2)+eps) to ~2e-10
      tss_ = tss0 + tz * tz;
      rt = rsq64(tss_);
      t  = tz * rt;
      double ncz2 = h + 2.0 * t * g + t * t * r;
      rn = rsq64(ncz2);
      ui = (g + t * r) * rn;
      if (pass == 0) u1 = ui;
    }
    double u2 = ui;
    double bz_new = bz0 + u2 * tz;
    double bb = bz_new * rt;             // bz_new / sqrt(tss_)
    double phi = 1.0 - t * t;            // xr' = phi*xr - t*P_i
    double gam = bb * t * rn;            // yr' = psi*yr - gam*Cz_i
    double psi = 1.0 - gam * t;

    if (l == 0) {
      out[OUT_U + i]   = (float)u2;
      out[OUT_TSS + i] = (float)tss_;
      out[OUT_BZ + i]  = (float)bz_new;
    }
    if (l < 33) {
      AWZT[l * 32 + i] = (float)(u1 * cx);
      APT [l * 32 + i] = (float)(t  * cx) + ((l == 1 + i) ? 1.0f : 0.0f);
      ACZT[l * 32 + i] = (float)(t  * cy) + ((l == 1 + i) ? 1.0f : 0.0f);
    }
    q = phi * phi * q - 2.0 * phi * t * pi + t * t * Pd;
    r = psi * psi * r - 2.0 * psi * gam * g + gam * gam * h;
    cx *= phi; if (l == 1 + i) cx -= t;
    cy *= psi; if (l == 1 + i) cy -= gam;
    if (l < 32) {
      pj = phi * pj - t * (double)rP[i];
      wj = phi * wj - t * (double)rW[i];
      ej = psi * ej - gam * (double)rC[i];
    }
  }
}

// j-outer, 64 resident f32 accumulators per thread: B_j loaded once, consumed.
__global__ __launch_bounds__(256) void out_kernel(
    const float* __restrict__ x, const float* __restrict__ y,
    const float* __restrict__ mux, const float* __restrict__ muy,
    const float* __restrict__ Wz, const float* __restrict__ Cz,
    const float* __restrict__ P, const int* __restrict__ np,
    const float* __restrict__ coef, float* __restrict__ out)
{
  const int b = blockIdx.x, tid = threadIdx.x;
  const float n1 = (float)(np[0] + 1);
  const float inv = 1.0f / (n1 + 1.0f);
  const float* AWZT = coef;
  const float* APT  = coef + 33 * NL;
  const float* ACZT = coef + 66 * NL;

  if (b < 1024) {
    const int k = b * 256 + tid;
    float xv = x[k], mv = mux[k];
    float mn = (mv * n1 + xv) * inv;
    out[OUT_MU_X + k] = mn;
    float accW[32], accP[32];
#pragma unroll
    for (int i = 0; i < 32; ++i) accW[i] = Wz[(size_t)i * NF + k];
#pragma unroll
    for (int i = 0; i < 32; ++i) accP[i] = 0.f;
    {
      float B0 = xv - mn;
#pragma unroll
      for (int i = 0; i < 32; ++i) {
        accW[i] += AWZT[i] * B0;
        accP[i] += APT[i] * B0;
      }
    }
#pragma unroll 4
    for (int j = 1; j < 33; ++j) {
      float Bj = P[(size_t)(j - 1) * NF + k];
      const float* cw = AWZT + j * 32;
      const float* cp = APT + j * 32;
#pragma unroll
      for (int i = 0; i < 32; ++i) {
        accW[i] += cw[i] * Bj;
        accP[i] += cp[i] * Bj;
      }
    }
#pragma unroll
    for (int i = 0; i < 32; ++i) out[OUT_WZ + (size_t)i * NF + k] = accW[i];
#pragma unroll
    for (int i = 0; i < 32; ++i) out[OUT_P + (size_t)i * NF + k] = accP[i];
  } else {
    const int k = (b - 1024) * 256 + tid;
    float yv = y[k], mv = muy[k];
    float mn = (mv * n1 + yv) * inv;
    out[OUT_MU_Y + k] = mn;
    float accC[32];
#pragma unroll
    for (int i = 0; i < 32; ++i) accC[i] = 0.f;
    {
      float B0 = yv - mn;
#pragma unroll
      for (int i = 0; i < 32; ++i) accC[i] += ACZT[i] * B0;
    }
#pragma unroll 4
    for (int j = 1; j < 33; ++j) {
      float Bj = Cz[(size_t)(j - 1) * NT + k];
      const float* cc = ACZT + j * 32;
#pragma unroll
      for (int i = 0; i < 32; ++i) accC[i] += cc[i] * Bj;
    }
#pragma unroll
    for (int i = 0; i < 32; ++i) out[OUT_CZ + (size_t)i * NT + k] = accC[i];
  }
}

extern "C" void kernel_launch(void* const* d_in, const int* in_sizes, int n_in,
                              void* d_out, int out_size, void* d_ws, size_t ws_size,
                              hipStream_t stream) {
  const float* x   = (const float*)d_in[0];
  const float* y   = (const float*)d_in[1];
  const float* mux = (const float*)d_in[2];
  const float* muy = (const float*)d_in[3];
  const float* u   = (const float*)d_in[4];
  const float* Wz  = (const float*)d_in[5];
  const float* Cz  = (const float*)d_in[6];
  const float* tss = (const float*)d_in[7];
  const float* bz  = (const float*)d_in[8];
  const float* P   = (const float*)d_in[9];
  const int*   n   = (const int*)d_in[10];
  float* ws  = (float*)d_ws;
  float* out = (float*)d_out;

  // GY (atomics) and GX (atomic-reduced) are adjacent -> one memset
  hipMemsetAsync(ws + WS_GY, 0, (size_t)(GYS * GYS + PBE) * sizeof(float), stream);
  gram_kernel<<<NBX + 32, 320, 0, stream>>>(x, y, mux, muy, Wz, Cz, P, n, ws);
  reduce_kernel<<<72, 256, 0, stream>>>(ws);
  solve_kernel<<<1, 64, 0, stream>>>(ws, u, tss, bz, ws + WS_COEF, out);
  out_kernel<<<1024 + 32, 256, 0, stream>>>(x, y, mux, muy, Wz, Cz, P, n, ws + WS_COEF, out);
}

// Round 4
// 228.147 us; speedup vs baseline: 1.1674x; 1.0217x over previous
//
#include <hip/hip_runtime.h>

// IPLS partial_fit (n > BURN_IN). Gram-reformulated.
// R9: (a) NBX 512->1024 (KS=256, NCHK=2; per-chunk geometry identical to R8).
// Grid was the occupancy limiter (544 blocks = 2.1/CU; LDS allows 3).
// (b) Partial accumulation into 128 slots via global atomicAdd (depth 8/addr
// -- avoids both R7's 500-deep single-copy serialization and a 9.3MB ws).
// (c) sdiag LDS atomics (the 1.35M bank-conflict source, 32-deep same-addr
// RMW in the convert phase) replaced by wave shfl-reduce + 1 global atomic
// per row. (d) Both chunks' loads issued up-front into ping-pong register
// buffers (vA/vB) -- no load latency exposure after prologue.
// solve keeps rsq64 chain; out_kernel unchanged.

#define NF 262144
#define NT 8192
#define NL 32
#define GYS 36
#define LDSW 260       // y-side row stride (floats): 256 + 4 pad

#define NBX 1024       // x-side K-slice blocks
#define KS  256        // K elems per block
#define CHK 128        // K elems per chunk (LDS resident)
#define NCHK 2
#define NSLOT 128      // partial-accumulation slots (blocks b, b+128, ... share)
#define GXW 68         // Gram row stride (cols 0..64 used)
#define PBE 2276       // slot entries: 33*68 + 32 diag
#define DIAG 2244      // 33*68

#define WS_PART 0
#define WS_GY   (NSLOT*PBE)          // 291328
#define WS_GX   (WS_GY + GYS*GYS)    // 292624
#define WS_COEF (WS_GX + PBE)        // 294900 (+3168 -> 298068 floats, 1.19MB)

#define OUT_MU_X 0
#define OUT_MU_Y 262144
#define OUT_U    270336
#define OUT_WZ   270368
#define OUT_CZ   8658976
#define OUT_TSS  8921120
#define OUT_BZ   8921152
#define OUT_P    8921184

typedef __attribute__((ext_vector_type(8))) short bf16x8;
typedef __attribute__((ext_vector_type(4))) float f32x4;

__device__ __forceinline__ float4 ld4(const float* p) { return *(const float4*)p; }

__device__ __forceinline__ unsigned int f2bf_rne(float f) {
  unsigned int t = __float_as_uint(f);
  t += 0x7FFFu + ((t >> 16) & 1u);
  return t >> 16;
}

// f64 rsqrt: v_rsq_f64 seed (~2^-23) + one Newton step -> ~3e-14 relative.
__device__ __forceinline__ double rsq64(double x) {
  double r = __builtin_amdgcn_rsq(x);
  r = r * (1.5 - 0.5 * x * r * r);
  return r;
}

__global__ __launch_bounds__(320) void gram_kernel(
    const float* __restrict__ x, const float* __restrict__ y,
    const float* __restrict__ mux, const float* __restrict__ muy,
    const float* __restrict__ Wz, const float* __restrict__ Cz,
    const float* __restrict__ P, const int* __restrict__ np,
    float* __restrict__ ws)
{
  __shared__ __align__(16) char smem[80 * CHK * 4 + 128];  // hi+lo planes
  const int tid = threadIdx.x;
  const int b = blockIdx.x;
  const float n1 = (float)(np[0] + 1);
  const float cmu = n1 / (n1 + 1.0f);   // xc = cmu*(x - mu_old)

  if (b < NBX) {
    // ---- x-side: bf16-split MFMA SYRK slice ----
    char* hB = smem;                        // hi plane: [80][128] bf16
    char* lB = smem + 80 * CHK * 2;         // lo plane
    float* PB = ws + WS_PART + (size_t)(b & (NSLOT - 1)) * PBE;

    {  // zero pad rows 65..79 (both planes), once; stays zero across chunks
      unsigned int* hz = (unsigned int*)hB;
      unsigned int* lz = (unsigned int*)lB;
      for (int i = tid; i < 960; i += 320) { hz[65 * 64 + i] = 0u; lz[65 * 64 + i] = 0u; }
    }

    f32x4 acc0 = {0.f, 0.f, 0.f, 0.f};
    f32x4 acc1 = acc0, acc2 = acc0;
    const int lane = tid & 63;
    const int w = tid >> 6;            // wave = N-tile 0..4 (cols w*16..w*16+15)
    const int col16 = lane & 15;
    const int kgrp = lane >> 4;        // 0..3
    const int swz = (col16 & 7) << 4;  // (row&7)<<4; row%8 == col16%8 for all frags

    float4 vA[7], vB[7]; float4 vmA, vmB;

    auto issue = [&](int c, float4* v, float4& vm) {
      const int kb = b * KS + c * CHK;
#pragma unroll
      for (int it = 0; it < 7; ++it) {
        int idx = tid + it * 320;
        if (idx < 2080) {
          int row = idx >> 5;
          int c4 = idx & 31;
          int k = kb + c4 * 4;
          const float* bp = (row == 0) ? (x + k)
                          : (row < 33) ? (P + (size_t)(row - 1) * NF + k)
                                       : (Wz + (size_t)(row - 33) * NF + k);
          v[it] = ld4(bp);
          if (it == 0 && row == 0) vm = ld4(mux + k);
        }
      }
    };

    // staged regs -> bf16 hi/lo planes; Wz rows: shfl-reduce sq -> 1 global atomic
    auto convert_write = [&](float4* v, float4& vm) {
#pragma unroll
      for (int it = 0; it < 7; ++it) {
        int idx = tid + it * 320;
        if (idx < 2080) {
          int row = idx >> 5;
          int c4 = idx & 31;
          float4 t4 = v[it];
          if (it == 0 && row == 0) {
            t4.x = cmu * (t4.x - vm.x); t4.y = cmu * (t4.y - vm.y);
            t4.z = cmu * (t4.z - vm.z); t4.w = cmu * (t4.w - vm.w);
          }
          if (row >= 33) {   // Wz diag: lanes of a wave-half share one row
            float sq = t4.x * t4.x + t4.y * t4.y + t4.z * t4.z + t4.w * t4.w;
            sq += __shfl_xor(sq, 1, 64);
            sq += __shfl_xor(sq, 2, 64);
            sq += __shfl_xor(sq, 4, 64);
            sq += __shfl_xor(sq, 8, 64);
            sq += __shfl_xor(sq, 16, 64);
            if ((tid & 31) == 0) atomicAdd(&PB[DIAG + row - 33], sq);
          }
          unsigned int b0 = __float_as_uint(t4.x), b1 = __float_as_uint(t4.y);
          unsigned int b2 = __float_as_uint(t4.z), b3 = __float_as_uint(t4.w);
          float h0 = __uint_as_float(b0 & 0xFFFF0000u);
          float h1 = __uint_as_float(b1 & 0xFFFF0000u);
          float h2 = __uint_as_float(b2 & 0xFFFF0000u);
          float h3 = __uint_as_float(b3 & 0xFFFF0000u);
          uint2 hw, lw;
          hw.x = (b0 >> 16) | ((b1 >> 16) << 16);
          hw.y = (b2 >> 16) | ((b3 >> 16) << 16);
          lw.x = f2bf_rne(t4.x - h0) | (f2bf_rne(t4.y - h1) << 16);
          lw.y = f2bf_rne(t4.z - h2) | (f2bf_rne(t4.w - h3) << 16);
          int off = ((row << 8) + (c4 << 3)) ^ ((row & 7) << 4);
          *(uint2*)(hB + off) = hw;
          *(uint2*)(lB + off) = lw;
        }
      }
    };

    auto compute_chunk = [&]() {
#pragma unroll
      for (int s = 0; s < 4; ++s) {
        const int kbyte = s * 64 + kgrp * 16;
        const int oa = ((col16 << 8) + kbyte) ^ swz;   // M-tile 0 (rows 0..15)
        const int ob = oa + (w << 12);                 // N-tile w
        bf16x8 bh = *(const bf16x8*)(hB + ob);
        bf16x8 bl = *(const bf16x8*)(lB + ob);
        bf16x8 a0h = *(const bf16x8*)(hB + oa);
        bf16x8 a0l = *(const bf16x8*)(lB + oa);
        acc0 = __builtin_amdgcn_mfma_f32_16x16x32_bf16(a0h, bh, acc0, 0, 0, 0);
        acc0 = __builtin_amdgcn_mfma_f32_16x16x32_bf16(a0h, bl, acc0, 0, 0, 0);
        acc0 = __builtin_amdgcn_mfma_f32_16x16x32_bf16(a0l, bh, acc0, 0, 0, 0);
        acc0 = __builtin_amdgcn_mfma_f32_16x16x32_bf16(a0l, bl, acc0, 0, 0, 0);
        bf16x8 a1h = *(const bf16x8*)(hB + oa + 4096);  // rows 16..31
        bf16x8 a1l = *(const bf16x8*)(lB + oa + 4096);
        acc1 = __builtin_amdgcn_mfma_f32_16x16x32_bf16(a1h, bh, acc1, 0, 0, 0);
        acc1 = __builtin_amdgcn_mfma_f32_16x16x32_bf16(a1h, bl, acc1, 0, 0, 0);
        acc1 = __builtin_amdgcn_mfma_f32_16x16x32_bf16(a1l, bh, acc1, 0, 0, 0);
        acc1 = __builtin_amdgcn_mfma_f32_16x16x32_bf16(a1l, bl, acc1, 0, 0, 0);
        bf16x8 a2h = *(const bf16x8*)(hB + oa + 8192);  // rows 32..47 (row 32 = P31)
        bf16x8 a2l = *(const bf16x8*)(lB + oa + 8192);
        acc2 = __builtin_amdgcn_mfma_f32_16x16x32_bf16(a2h, bh, acc2, 0, 0, 0);
        acc2 = __builtin_amdgcn_mfma_f32_16x16x32_bf16(a2h, bl, acc2, 0, 0, 0);
        acc2 = __builtin_amdgcn_mfma_f32_16x16x32_bf16(a2l, bh, acc2, 0, 0, 0);
        acc2 = __builtin_amdgcn_mfma_f32_16x16x32_bf16(a2l, bl, acc2, 0, 0, 0);
      }
    };

    issue(0, vA, vmA);                 // all loads for both chunks in flight
    issue(1, vB, vmB);
    convert_write(vA, vmA);            // waits only vA (older in queue)
    __syncthreads();
    compute_chunk();                   // chunk 0
    __syncthreads();
    convert_write(vB, vmB);
    __syncthreads();
    compute_chunk();                   // chunk 1

    // accumulate into slot (8 blocks share a slot -> shallow atomic chains)
    const int vcol = w * 16 + col16;
    if (vcol < 65) {
#pragma unroll
      for (int r2 = 0; r2 < 4; ++r2) {
        int u = kgrp * 4 + r2;
        atomicAdd(&PB[u * GXW + vcol], acc0[r2]);           // rows 0..15
        atomicAdd(&PB[(16 + u) * GXW + vcol], acc1[r2]);    // rows 16..31
      }
      if (kgrp == 0) atomicAdd(&PB[32 * GXW + vcol], acc2[0]);  // row 32 only
    }
  } else {
    // ---- y-side: 36 rows [yc, Cz_0..31, zeros]; loads batched to regs ----
    float* lds = (float*)smem;   // 36*260*4 = 37.4KB <= 41KB alias
    float* GY = ws + WS_GY;
    const int yb = b - NBX;
    int gu = 0, gv = 0; bool active = (tid < 45);
    if (active) {
      int pp = tid;
      for (int g = 0; g < 9; ++g) {
        int cnt = 9 - g;
        if (pp < cnt) { gu = g; gv = g + pp; break; }
        pp -= cnt;
      }
    }
    float acc[16];
#pragma unroll
    for (int i = 0; i < 16; ++i) acc[i] = 0.f;
    const int wb = yb * 256;
    float4 vy[8]; float4 vmy;
#pragma unroll
    for (int it = 0; it < 8; ++it) {
      int idx = tid + it * 320;
      if (idx < 2304) {
        int row = idx >> 6;
        int c4 = idx & 63;
        int k = wb + c4 * 4;
        if (row == 0) {
          vy[it] = ld4(y + k);
          if (it == 0) vmy = ld4(muy + k);
        } else if (row < 33) {
          vy[it] = ld4(Cz + (size_t)(row - 1) * NT + k);
        } else {
          vy[it] = make_float4(0.f, 0.f, 0.f, 0.f);
        }
      }
    }
#pragma unroll
    for (int it = 0; it < 8; ++it) {
      int idx = tid + it * 320;
      if (idx < 2304) {
        int row = idx >> 6;
        int c4 = idx & 63;
        float4 t4 = vy[it];
        if (it == 0 && row == 0) {
          t4.x = cmu * (t4.x - vmy.x); t4.y = cmu * (t4.y - vmy.y);
          t4.z = cmu * (t4.z - vmy.z); t4.w = cmu * (t4.w - vmy.w);
        }
        *(float4*)&lds[row * LDSW + c4 * 4] = t4;
      }
    }
    __syncthreads();
    if (active) {
      const int ub = 4 * gu * LDSW, vb = 4 * gv * LDSW;
      for (int c = 0; c < 64; ++c) {
        float4 av[4], bv[4];
#pragma unroll
        for (int r = 0; r < 4; ++r) av[r] = *(const float4*)&lds[ub + r * LDSW + c * 4];
#pragma unroll
        for (int s = 0; s < 4; ++s) bv[s] = *(const float4*)&lds[vb + s * LDSW + c * 4];
#pragma unroll
        for (int r = 0; r < 4; ++r)
#pragma unroll
          for (int s = 0; s < 4; ++s)
            acc[r * 4 + s] += av[r].x * bv[s].x + av[r].y * bv[s].y +
                              av[r].z * bv[s].z + av[r].w * bv[s].w;
      }
#pragma unroll
      for (int r = 0; r < 4; ++r)
#pragma unroll
        for (int s = 0; s < 4; ++s) {
          int u = 4 * gu + r, v = 4 * gv + s;
          if (u < 33 && v < 33) {
            float val = acc[r * 4 + s];
            atomicAdd(&GY[u * GYS + v], val);
            if (gu != gv) atomicAdd(&GY[v * GYS + u], val);
          }
        }
    }
  }
}

// sum 128 slots -> GX: 4 sub-chunks of 32 slots, atomicAdd (4 deep/addr)
__global__ __launch_bounds__(256) void reduce_kernel(float* __restrict__ ws) {
  const int e = (blockIdx.x % 9) * 256 + threadIdx.x;
  const int c = blockIdx.x / 9;          // 0..3
  if (e < PBE) {
    const float* PB = ws + WS_PART + (size_t)(c * 32) * PBE + e;
    float s0 = 0.f, s1 = 0.f, s2 = 0.f, s3 = 0.f;
#pragma unroll
    for (int j = 0; j < 32; j += 4) {
      s0 += PB[(size_t)j * PBE];
      s1 += PB[(size_t)(j + 1) * PBE];
      s2 += PB[(size_t)(j + 2) * PBE];
      s3 += PB[(size_t)(j + 3) * PBE];
    }
    atomicAdd(ws + WS_GX + e, (s0 + s1) + (s2 + s3));
  }
}

// One wave: f64 scalar recurrences for all 32 components; Gram rows preloaded
// into registers; i-loop fully unrolled (compile-time __shfl indices).
// Critical chain uses rsq64 (v_rsq_f64 + 1 Newton) -- no f64 sqrt/div.
__global__ void solve_kernel(const float* __restrict__ ws,
                             const float* __restrict__ u_in,
                             const float* __restrict__ tss_in,
                             const float* __restrict__ bz_in,
                             float* __restrict__ coef,
                             float* __restrict__ out)
{
  const int l = threadIdx.x;  // 0..63
  const float* GX = ws + WS_GX;
  const float* GY = ws + WS_GY;
  float* AWZT = coef;               // 33 x 32
  float* APT  = coef + 33 * NL;     // 33 x 32 (+P_i identity folded)
  float* ACZT = coef + 66 * NL;     // 33 x 32 (+Cz_i identity folded)

  float rP[32], rW[32], rC[32];
#pragma unroll
  for (int i = 0; i < 32; ++i) rP[i] = GX[(1 + i) * GXW + 1 + l];
#pragma unroll
  for (int i = 0; i < 32; ++i) rW[i] = (l < 32) ? GX[(1 + i) * GXW + 33 + l] : 0.f;
#pragma unroll
  for (int i = 0; i < 32; ++i) rC[i] = GY[(1 + i) * GYS + 1 + l];
  float dS  = (l < 32) ? GX[DIAG + l] : 0.f;  // ||Wz_l||^2
  float u0l = (l < 32) ? u_in[l]   : 0.f;
  float t0l = (l < 32) ? tss_in[l] : 0.f;
  float b0l = (l < 32) ? bz_in[l]  : 0.f;

  double q = (double)GX[0];                       // ||xr||^2
  double r = (double)GY[0];                       // ||yr||^2
  double pj = (l < 32) ? (double)GX[1 + l]  : 0.0;
  double wj = (l < 32) ? (double)GX[33 + l] : 0.0;
  double ej = (l < 32) ? (double)GY[1 + l]  : 0.0;
  double cx = (l == 0) ? 1.0 : 0.0;
  double cy = (l == 0) ? 1.0 : 0.0;

#pragma unroll
  for (int i = 0; i < NL; ++i) {
    double a  = __shfl(wj, i, 64);
    double g  = __shfl(ej, i, 64);
    double pi = __shfl(pj, i, 64);
    double s  = (double)__shfl(dS, i, 64);
    double h  = (double)__shfl(rC[i], i, 64);      // GY diag (1+i,1+i)
    double Pd = (double)__shfl(rP[i], i, 64);      // GX diag (1+i,1+i)
    double u0   = (double)__shfl(u0l, i, 64);
    double tss0 = (double)__shfl(t0l, i, 64);
    double bz0  = (double)__shfl(b0l, i, 64);

    double ui = u0, u1 = 0.0, tz = 0.0, tss_ = 0.0, t = 0.0;
    double rt = 0.0, rn = 0.0;
#pragma unroll
    for (int pass = 0; pass < 2; ++pass) {
      double num = a + ui * q;
      double s2  = s + 2.0 * ui * a + ui * ui * q;
      double rs  = rsq64(s2);
      tz = num * rs * (1.0 - 1e-7 * rs);     // num/(sqrt(s2)+eps) to ~2e-10
      tss_ = tss0 + tz * tz;
      rt = rsq64(tss_);
      t  = tz * rt;
      double ncz2 = h + 2.0 * t * g + t * t * r;
      rn = rsq64(ncz2);
      ui = (g + t * r) * rn;
      if (pass == 0) u1 = ui;
    }
    double u2 = ui;
    double bz_new = bz0 + u2 * tz;
    double bb = bz_new * rt;             // bz_new / sqrt(tss_)
    double phi = 1.0 - t * t;            // xr' = phi*xr - t*P_i
    double gam = bb * t * rn;            // yr' = psi*yr - gam*Cz_i
    double psi = 1.0 - gam * t;

    if (l == 0) {
      out[OUT_U + i]   = (float)u2;
      out[OUT_TSS + i] = (float)tss_;
      out[OUT_BZ + i]  = (float)bz_new;
    }
    if (l < 33) {
      AWZT[l * 32 + i] = (float)(u1 * cx);
      APT [l * 32 + i] = (float)(t  * cx) + ((l == 1 + i) ? 1.0f : 0.0f);
      ACZT[l * 32 + i] = (float)(t  * cy) + ((l == 1 + i) ? 1.0f : 0.0f);
    }
    q = phi * phi * q - 2.0 * phi * t * pi + t * t * Pd;
    r = psi * psi * r - 2.0 * psi * gam * g + gam * gam * h;
    cx *= phi; if (l == 1 + i) cx -= t;
    cy *= psi; if (l == 1 + i) cy -= gam;
    if (l < 32) {
      pj = phi * pj - t * (double)rP[i];
      wj = phi * wj - t * (double)rW[i];
      ej = psi * ej - gam * (double)rC[i];
    }
  }
}

// j-outer, 64 resident f32 accumulators per thread: B_j loaded once, consumed.
__global__ __launch_bounds__(256) void out_kernel(
    const float* __restrict__ x, const float* __restrict__ y,
    const float* __restrict__ mux, const float* __restrict__ muy,
    const float* __restrict__ Wz, const float* __restrict__ Cz,
    const float* __restrict__ P, const int* __restrict__ np,
    const float* __restrict__ coef, float* __restrict__ out)
{
  const int b = blockIdx.x, tid = threadIdx.x;
  const float n1 = (float)(np[0] + 1);
  const float inv = 1.0f / (n1 + 1.0f);
  const float* AWZT = coef;
  const float* APT  = coef + 33 * NL;
  const float* ACZT = coef + 66 * NL;

  if (b < 1024) {
    const int k = b * 256 + tid;
    float xv = x[k], mv = mux[k];
    float mn = (mv * n1 + xv) * inv;
    out[OUT_MU_X + k] = mn;
    float accW[32], accP[32];
#pragma unroll
    for (int i = 0; i < 32; ++i) accW[i] = Wz[(size_t)i * NF + k];
#pragma unroll
    for (int i = 0; i < 32; ++i) accP[i] = 0.f;
    {
      float B0 = xv - mn;
#pragma unroll
      for (int i = 0; i < 32; ++i) {
        accW[i] += AWZT[i] * B0;
        accP[i] += APT[i] * B0;
      }
    }
#pragma unroll 4
    for (int j = 1; j < 33; ++j) {
      float Bj = P[(size_t)(j - 1) * NF + k];
      const float* cw = AWZT + j * 32;
      const float* cp = APT + j * 32;
#pragma unroll
      for (int i = 0; i < 32; ++i) {
        accW[i] += cw[i] * Bj;
        accP[i] += cp[i] * Bj;
      }
    }
#pragma unroll
    for (int i = 0; i < 32; ++i) out[OUT_WZ + (size_t)i * NF + k] = accW[i];
#pragma unroll
    for (int i = 0; i < 32; ++i) out[OUT_P + (size_t)i * NF + k] = accP[i];
  } else {
    const int k = (b - 1024) * 256 + tid;
    float yv = y[k], mv = muy[k];
    float mn = (mv * n1 + yv) * inv;
    out[OUT_MU_Y + k] = mn;
    float accC[32];
#pragma unroll
    for (int i = 0; i < 32; ++i) accC[i] = 0.f;
    {
      float B0 = yv - mn;
#pragma unroll
      for (int i = 0; i < 32; ++i) accC[i] += ACZT[i] * B0;
    }
#pragma unroll 4
    for (int j = 1; j < 33; ++j) {
      float Bj = Cz[(size_t)(j - 1) * NT + k];
      const float* cc = ACZT + j * 32;
#pragma unroll
      for (int i = 0; i < 32; ++i) accC[i] += cc[i] * Bj;
    }
#pragma unroll
    for (int i = 0; i < 32; ++i) out[OUT_CZ + (size_t)i * NT + k] = accC[i];
  }
}

extern "C" void kernel_launch(void* const* d_in, const int* in_sizes, int n_in,
                              void* d_out, int out_size, void* d_ws, size_t ws_size,
                              hipStream_t stream) {
  const float* x   = (const float*)d_in[0];
  const float* y   = (const float*)d_in[1];
  const float* mux = (const float*)d_in[2];
  const float* muy = (const float*)d_in[3];
  const float* u   = (const float*)d_in[4];
  const float* Wz  = (const float*)d_in[5];
  const float* Cz  = (const float*)d_in[6];
  const float* tss = (const float*)d_in[7];
  const float* bz  = (const float*)d_in[8];
  const float* P   = (const float*)d_in[9];
  const int*   n   = (const int*)d_in[10];
  float* ws  = (float*)d_ws;
  float* out = (float*)d_out;

  // slots + GY + GX all atomically accumulated, contiguous -> one memset (1.18MB)
  hipMemsetAsync(ws, 0, (size_t)(NSLOT * PBE + GYS * GYS + PBE) * sizeof(float), stream);
  gram_kernel<<<NBX + 32, 320, 0, stream>>>(x, y, mux, muy, Wz, Cz, P, n, ws);
  reduce_kernel<<<36, 256, 0, stream>>>(ws);
  solve_kernel<<<1, 64, 0, stream>>>(ws, u, tss, bz, ws + WS_COEF, out);
  out_kernel<<<1024 + 32, 256, 0, stream>>>(x, y, mux, muy, Wz, Cz, P, n, ws + WS_COEF, out);
}

// Round 5
// 220.366 us; speedup vs baseline: 1.2086x; 1.0353x over previous
//
#include <hip/hip_runtime.h>

// IPLS partial_fit (n > BURN_IN). Gram-reformulated.
// R10: (a) gram x-side: NBX=1024 (KS=256, NCHK=2) for grid residency, but with
// R8's PROVEN single-reg-set pipeline: issue(c+1) sits between the post-convert
// barrier and compute(c), so HBM latency hides under MFMA. (R9 held two reg
// sets -> compiler sank the loads (VGPR=64 proves it) and the pipeline died.)
// (b) Partials: depth-2 atomicAdd into 512 slots (blocks b, b+512 share).
// (c) reduce and solve fused via last-block pattern (threadfence + counter):
// one fewer launch, solve starts the moment GX lands.
// Bank-conflict counter (1.35M) proven invariant across structures in R8/R9 ->
// it's the inherent wrap pattern, not a fixable stall; ignored from here on.

#define NF 262144
#define NT 8192
#define NL 32
#define GYS 36
#define LDSW 260       // y-side row stride (floats): 256 + 4 pad

#define NBX 1024       // x-side K-slice blocks
#define KS  256        // K elems per block
#define CHK 128        // K elems per chunk (LDS resident)
#define NSLOT 512      // partial slots; blocks b and b+512 share slot b
#define GXW 68         // Gram row stride (cols 0..64 used)
#define PBE 2276       // slot entries: 33*68 + 32 diag
#define DIAG 2244      // 33*68

#define WS_PART 0
#define WS_GY   (NSLOT*PBE)          // 1165312
#define WS_GX   (WS_GY + GYS*GYS)    // 1166608
#define WS_CNT  (WS_GX + PBE)        // 1168884 (int counter)
#define WS_COEF (WS_CNT + 4)         // 1168888 (+3168 -> 1172056 floats, 4.69MB)

#define OUT_MU_X 0
#define OUT_MU_Y 262144
#define OUT_U    270336
#define OUT_WZ   270368
#define OUT_CZ   8658976
#define OUT_TSS  8921120
#define OUT_BZ   8921152
#define OUT_P    8921184

typedef __attribute__((ext_vector_type(8))) short bf16x8;
typedef __attribute__((ext_vector_type(4))) float f32x4;

__device__ __forceinline__ float4 ld4(const float* p) { return *(const float4*)p; }

__device__ __forceinline__ unsigned int f2bf_rne(float f) {
  unsigned int t = __float_as_uint(f);
  t += 0x7FFFu + ((t >> 16) & 1u);
  return t >> 16;
}

// f64 rsqrt: v_rsq_f64 seed (~2^-23) + one Newton step -> ~3e-14 relative.
__device__ __forceinline__ double rsq64(double x) {
  double r = __builtin_amdgcn_rsq(x);
  r = r * (1.5 - 0.5 * x * r * r);
  return r;
}

__global__ __launch_bounds__(320) void gram_kernel(
    const float* __restrict__ x, const float* __restrict__ y,
    const float* __restrict__ mux, const float* __restrict__ muy,
    const float* __restrict__ Wz, const float* __restrict__ Cz,
    const float* __restrict__ P, const int* __restrict__ np,
    float* __restrict__ ws)
{
  __shared__ __align__(16) char smem[80 * CHK * 4 + 128];  // hi+lo planes
  const int tid = threadIdx.x;
  const int b = blockIdx.x;
  const float n1 = (float)(np[0] + 1);
  const float cmu = n1 / (n1 + 1.0f);   // xc = cmu*(x - mu_old)

  if (b < NBX) {
    // ---- x-side: bf16-split MFMA SYRK slice ----
    char* hB = smem;                        // hi plane: [80][128] bf16
    char* lB = smem + 80 * CHK * 2;         // lo plane
    float* PB = ws + WS_PART + (size_t)(b & (NSLOT - 1)) * PBE;

    {  // zero pad rows 65..79 (both planes), once; stays zero across chunks
      unsigned int* hz = (unsigned int*)hB;
      unsigned int* lz = (unsigned int*)lB;
      for (int i = tid; i < 960; i += 320) { hz[65 * 64 + i] = 0u; lz[65 * 64 + i] = 0u; }
    }

    f32x4 acc0 = {0.f, 0.f, 0.f, 0.f};
    f32x4 acc1 = acc0, acc2 = acc0;
    const int lane = tid & 63;
    const int w = tid >> 6;            // wave = N-tile 0..4 (cols w*16..w*16+15)
    const int col16 = lane & 15;
    const int kgrp = lane >> 4;        // 0..3
    const int swz = (col16 & 7) << 4;  // (row&7)<<4; row%8 == col16%8 for all frags

    float4 v[7]; float4 vm0;           // ONE live staging set (fits VGPR budget)

    auto issue = [&](int c) {
      const int kb = b * KS + c * CHK;
#pragma unroll
      for (int it = 0; it < 7; ++it) {
        int idx = tid + it * 320;
        if (idx < 2080) {
          int row = idx >> 5;
          int c4 = idx & 31;
          int k = kb + c4 * 4;
          const float* bp = (row == 0) ? (x + k)
                          : (row < 33) ? (P + (size_t)(row - 1) * NF + k)
                                       : (Wz + (size_t)(row - 33) * NF + k);
          v[it] = ld4(bp);
          if (it == 0 && row == 0) vm0 = ld4(mux + k);
        }
      }
    };

    // staged regs -> bf16 hi/lo planes; Wz rows: half-wave shfl-reduce -> 1 atomic
    auto convert_write = [&]() {
#pragma unroll
      for (int it = 0; it < 7; ++it) {
        int idx = tid + it * 320;
        if (idx < 2080) {
          int row = idx >> 5;
          int c4 = idx & 31;
          float4 t4 = v[it];
          if (it == 0 && row == 0) {
            t4.x = cmu * (t4.x - vm0.x); t4.y = cmu * (t4.y - vm0.y);
            t4.z = cmu * (t4.z - vm0.z); t4.w = cmu * (t4.w - vm0.w);
          }
          if (row >= 33) {   // Wz diag: 32 lanes of a half-wave share one row
            float sq = t4.x * t4.x + t4.y * t4.y + t4.z * t4.z + t4.w * t4.w;
            sq += __shfl_xor(sq, 1, 64);
            sq += __shfl_xor(sq, 2, 64);
            sq += __shfl_xor(sq, 4, 64);
            sq += __shfl_xor(sq, 8, 64);
            sq += __shfl_xor(sq, 16, 64);
            if ((tid & 31) == 0) atomicAdd(&PB[DIAG + row - 33], sq);
          }
          unsigned int b0 = __float_as_uint(t4.x), b1 = __float_as_uint(t4.y);
          unsigned int b2 = __float_as_uint(t4.z), b3 = __float_as_uint(t4.w);
          float h0 = __uint_as_float(b0 & 0xFFFF0000u);
          float h1 = __uint_as_float(b1 & 0xFFFF0000u);
          float h2 = __uint_as_float(b2 & 0xFFFF0000u);
          float h3 = __uint_as_float(b3 & 0xFFFF0000u);
          uint2 hw, lw;
          hw.x = (b0 >> 16) | ((b1 >> 16) << 16);
          hw.y = (b2 >> 16) | ((b3 >> 16) << 16);
          lw.x = f2bf_rne(t4.x - h0) | (f2bf_rne(t4.y - h1) << 16);
          lw.y = f2bf_rne(t4.z - h2) | (f2bf_rne(t4.w - h3) << 16);
          int off = ((row << 8) + (c4 << 3)) ^ ((row & 7) << 4);
          *(uint2*)(hB + off) = hw;
          *(uint2*)(lB + off) = lw;
        }
      }
    };

    auto compute_chunk = [&]() {
#pragma unroll
      for (int s = 0; s < 4; ++s) {
        const int kbyte = s * 64 + kgrp * 16;
        const int oa = ((col16 << 8) + kbyte) ^ swz;   // M-tile 0 (rows 0..15)
        const int ob = oa + (w << 12);                 // N-tile w
        bf16x8 bh = *(const bf16x8*)(hB + ob);
        bf16x8 bl = *(const bf16x8*)(lB + ob);
        bf16x8 a0h = *(const bf16x8*)(hB + oa);
        bf16x8 a0l = *(const bf16x8*)(lB + oa);
        acc0 = __builtin_amdgcn_mfma_f32_16x16x32_bf16(a0h, bh, acc0, 0, 0, 0);
        acc0 = __builtin_amdgcn_mfma_f32_16x16x32_bf16(a0h, bl, acc0, 0, 0, 0);
        acc0 = __builtin_amdgcn_mfma_f32_16x16x32_bf16(a0l, bh, acc0, 0, 0, 0);
        acc0 = __builtin_amdgcn_mfma_f32_16x16x32_bf16(a0l, bl, acc0, 0, 0, 0);
        bf16x8 a1h = *(const bf16x8*)(hB + oa + 4096);  // rows 16..31
        bf16x8 a1l = *(const bf16x8*)(lB + oa + 4096);
        acc1 = __builtin_amdgcn_mfma_f32_16x16x32_bf16(a1h, bh, acc1, 0, 0, 0);
        acc1 = __builtin_amdgcn_mfma_f32_16x16x32_bf16(a1h, bl, acc1, 0, 0, 0);
        acc1 = __builtin_amdgcn_mfma_f32_16x16x32_bf16(a1l, bh, acc1, 0, 0, 0);
        acc1 = __builtin_amdgcn_mfma_f32_16x16x32_bf16(a1l, bl, acc1, 0, 0, 0);
        bf16x8 a2h = *(const bf16x8*)(hB + oa + 8192);  // rows 32..47 (row 32 = P31)
        bf16x8 a2l = *(const bf16x8*)(lB + oa + 8192);
        acc2 = __builtin_amdgcn_mfma_f32_16x16x32_bf16(a2h, bh, acc2, 0, 0, 0);
        acc2 = __builtin_amdgcn_mfma_f32_16x16x32_bf16(a2h, bl, acc2, 0, 0, 0);
        acc2 = __builtin_amdgcn_mfma_f32_16x16x32_bf16(a2l, bh, acc2, 0, 0, 0);
        acc2 = __builtin_amdgcn_mfma_f32_16x16x32_bf16(a2l, bl, acc2, 0, 0, 0);
      }
    };

    // R8-proven pipeline: one live reg set; next chunk's loads issued right
    // after the post-convert barrier -> latency hides under compute.
    issue(0);
    convert_write();
    __syncthreads();
    issue(1);
    compute_chunk();                   // chunk 0 (chunk-1 loads in flight)
    __syncthreads();
    convert_write();
    __syncthreads();
    compute_chunk();                   // chunk 1

    // accumulate into slot (2 blocks share a slot -> depth-2 atomic chains)
    const int vcol = w * 16 + col16;
    if (vcol < 65) {
#pragma unroll
      for (int r2 = 0; r2 < 4; ++r2) {
        int u = kgrp * 4 + r2;
        atomicAdd(&PB[u * GXW + vcol], acc0[r2]);           // rows 0..15
        atomicAdd(&PB[(16 + u) * GXW + vcol], acc1[r2]);    // rows 16..31
      }
      if (kgrp == 0) atomicAdd(&PB[32 * GXW + vcol], acc2[0]);  // row 32 only
    }
  } else {
    // ---- y-side: 36 rows [yc, Cz_0..31, zeros]; loads batched to regs ----
    float* lds = (float*)smem;   // 36*260*4 = 37.4KB <= 41KB alias
    float* GY = ws + WS_GY;
    const int yb = b - NBX;
    int gu = 0, gv = 0; bool active = (tid < 45);
    if (active) {
      int pp = tid;
      for (int g = 0; g < 9; ++g) {
        int cnt = 9 - g;
        if (pp < cnt) { gu = g; gv = g + pp; break; }
        pp -= cnt;
      }
    }
    float acc[16];
#pragma unroll
    for (int i = 0; i < 16; ++i) acc[i] = 0.f;
    const int wb = yb * 256;
    float4 vy[8]; float4 vmy;
#pragma unroll
    for (int it = 0; it < 8; ++it) {
      int idx = tid + it * 320;
      if (idx < 2304) {
        int row = idx >> 6;
        int c4 = idx & 63;
        int k = wb + c4 * 4;
        if (row == 0) {
          vy[it] = ld4(y + k);
          if (it == 0) vmy = ld4(muy + k);
        } else if (row < 33) {
          vy[it] = ld4(Cz + (size_t)(row - 1) * NT + k);
        } else {
          vy[it] = make_float4(0.f, 0.f, 0.f, 0.f);
        }
      }
    }
#pragma unroll
    for (int it = 0; it < 8; ++it) {
      int idx = tid + it * 320;
      if (idx < 2304) {
        int row = idx >> 6;
        int c4 = idx & 63;
        float4 t4 = vy[it];
        if (it == 0 && row == 0) {
          t4.x = cmu * (t4.x - vmy.x); t4.y = cmu * (t4.y - vmy.y);
          t4.z = cmu * (t4.z - vmy.z); t4.w = cmu * (t4.w - vmy.w);
        }
        *(float4*)&lds[row * LDSW + c4 * 4] = t4;
      }
    }
    __syncthreads();
    if (active) {
      const int ub = 4 * gu * LDSW, vb = 4 * gv * LDSW;
      for (int c = 0; c < 64; ++c) {
        float4 av[4], bv[4];
#pragma unroll
        for (int r = 0; r < 4; ++r) av[r] = *(const float4*)&lds[ub + r * LDSW + c * 4];
#pragma unroll
        for (int s = 0; s < 4; ++s) bv[s] = *(const float4*)&lds[vb + s * LDSW + c * 4];
#pragma unroll
        for (int r = 0; r < 4; ++r)
#pragma unroll
          for (int s = 0; s < 4; ++s)
            acc[r * 4 + s] += av[r].x * bv[s].x + av[r].y * bv[s].y +
                              av[r].z * bv[s].z + av[r].w * bv[s].w;
      }
#pragma unroll
      for (int r = 0; r < 4; ++r)
#pragma unroll
        for (int s = 0; s < 4; ++s) {
          int u = 4 * gu + r, v = 4 * gv + s;
          if (u < 33 && v < 33) {
            float val = acc[r * 4 + s];
            atomicAdd(&GY[u * GYS + v], val);
            if (gu != gv) atomicAdd(&GY[v * GYS + u], val);
          }
        }
    }
  }
}

// One wave: f64 scalar recurrences for all 32 components (rsq64 chain).
__device__ __forceinline__ void solve_body(
    const float* __restrict__ ws, const float* __restrict__ u_in,
    const float* __restrict__ tss_in, const float* __restrict__ bz_in,
    float* __restrict__ coef, float* __restrict__ out)
{
  const int l = threadIdx.x;  // 0..63
  const float* GX = ws + WS_GX;
  const float* GY = ws + WS_GY;
  float* AWZT = coef;               // 33 x 32
  float* APT  = coef + 33 * NL;     // 33 x 32 (+P_i identity folded)
  float* ACZT = coef + 66 * NL;     // 33 x 32 (+Cz_i identity folded)

  float rP[32], rW[32], rC[32];
#pragma unroll
  for (int i = 0; i < 32; ++i) rP[i] = GX[(1 + i) * GXW + 1 + l];
#pragma unroll
  for (int i = 0; i < 32; ++i) rW[i] = (l < 32) ? GX[(1 + i) * GXW + 33 + l] : 0.f;
#pragma unroll
  for (int i = 0; i < 32; ++i) rC[i] = GY[(1 + i) * GYS + 1 + l];
  float dS  = (l < 32) ? GX[DIAG + l] : 0.f;  // ||Wz_l||^2
  float u0l = (l < 32) ? u_in[l]   : 0.f;
  float t0l = (l < 32) ? tss_in[l] : 0.f;
  float b0l = (l < 32) ? bz_in[l]  : 0.f;

  double q = (double)GX[0];                       // ||xr||^2
  double r = (double)GY[0];                       // ||yr||^2
  double pj = (l < 32) ? (double)GX[1 + l]  : 0.0;
  double wj = (l < 32) ? (double)GX[33 + l] : 0.0;
  double ej = (l < 32) ? (double)GY[1 + l]  : 0.0;
  double cx = (l == 0) ? 1.0 : 0.0;
  double cy = (l == 0) ? 1.0 : 0.0;

#pragma unroll
  for (int i = 0; i < NL; ++i) {
    double a  = __shfl(wj, i, 64);
    double g  = __shfl(ej, i, 64);
    double pi = __shfl(pj, i, 64);
    double s  = (double)__shfl(dS, i, 64);
    double h  = (double)__shfl(rC[i], i, 64);      // GY diag (1+i,1+i)
    double Pd = (double)__shfl(rP[i], i, 64);      // GX diag (1+i,1+i)
    double u0   = (double)__shfl(u0l, i, 64);
    double tss0 = (double)__shfl(t0l, i, 64);
    double bz0  = (double)__shfl(b0l, i, 64);

    double ui = u0, u1 = 0.0, tz = 0.0, tss_ = 0.0, t = 0.0;
    double rt = 0.0, rn = 0.0;
#pragma unroll
    for (int pass = 0; pass < 2; ++pass) {
      double num = a + ui * q;
      double s2  = s + 2.0 * ui * a + ui * ui * q;
      double rs  = rsq64(s2);
      tz = num * rs * (1.0 - 1e-7 * rs);     // num/(sqrt(s2)+eps) to ~2e-10
      tss_ = tss0 + tz * tz;
      rt = rsq64(tss_);
      t  = tz * rt;
      double ncz2 = h + 2.0 * t * g + t * t * r;
      rn = rsq64(ncz2);
      ui = (g + t * r) * rn;
      if (pass == 0) u1 = ui;
    }
    double u2 = ui;
    double bz_new = bz0 + u2 * tz;
    double bb = bz_new * rt;             // bz_new / sqrt(tss_)
    double phi = 1.0 - t * t;            // xr' = phi*xr - t*P_i
    double gam = bb * t * rn;            // yr' = psi*yr - gam*Cz_i
    double psi = 1.0 - gam * t;

    if (l == 0) {
      out[OUT_U + i]   = (float)u2;
      out[OUT_TSS + i] = (float)tss_;
      out[OUT_BZ + i]  = (float)bz_new;
    }
    if (l < 33) {
      AWZT[l * 32 + i] = (float)(u1 * cx);
      APT [l * 32 + i] = (float)(t  * cx) + ((l == 1 + i) ? 1.0f : 0.0f);
      ACZT[l * 32 + i] = (float)(t  * cy) + ((l == 1 + i) ? 1.0f : 0.0f);
    }
    q = phi * phi * q - 2.0 * phi * t * pi + t * t * Pd;
    r = psi * psi * r - 2.0 * psi * gam * g + gam * gam * h;
    cx *= phi; if (l == 1 + i) cx -= t;
    cy *= psi; if (l == 1 + i) cy -= gam;
    if (l < 32) {
      pj = phi * pj - t * (double)rP[i];
      wj = phi * wj - t * (double)rW[i];
      ej = psi * ej - gam * (double)rC[i];
    }
  }
}

// fused reduce (512 slots -> GX, 8 chunks x 9 eblocks, depth-8 atomics)
// + last-block inline solve (threadfence + completion counter).
__global__ __launch_bounds__(256) void redsolve_kernel(
    float* __restrict__ ws, const float* __restrict__ u_in,
    const float* __restrict__ tss_in, const float* __restrict__ bz_in,
    float* __restrict__ coef, float* __restrict__ out)
{
  const int e = (blockIdx.x % 9) * 256 + threadIdx.x;
  const int c = blockIdx.x / 9;          // 0..7
  if (e < PBE) {
    const float* PB = ws + WS_PART + (size_t)(c * 64) * PBE + e;
    float s0 = 0.f, s1 = 0.f, s2 = 0.f, s3 = 0.f;
#pragma unroll
    for (int j = 0; j < 64; j += 4) {
      s0 += PB[(size_t)j * PBE];
      s1 += PB[(size_t)(j + 1) * PBE];
      s2 += PB[(size_t)(j + 2) * PBE];
      s3 += PB[(size_t)(j + 3) * PBE];
    }
    atomicAdd(ws + WS_GX + e, (s0 + s1) + (s2 + s3));
  }
  __threadfence();                       // release: GX adds visible device-wide
  __shared__ int lastflag;
  if (threadIdx.x == 0) {
    int old = atomicAdd((int*)(ws + WS_CNT), 1);
    lastflag = (old == 71);
  }
  __syncthreads();
  if (!lastflag) return;
  __threadfence();                       // acquire: see all blocks' GX adds
  if (threadIdx.x < 64) solve_body(ws, u_in, tss_in, bz_in, coef, out);
}

// j-outer, 64 resident f32 accumulators per thread: B_j loaded once, consumed.
__global__ __launch_bounds__(256) void out_kernel(
    const float* __restrict__ x, const float* __restrict__ y,
    const float* __restrict__ mux, const float* __restrict__ muy,
    const float* __restrict__ Wz, const float* __restrict__ Cz,
    const float* __restrict__ P, const int* __restrict__ np,
    const float* __restrict__ coef, float* __restrict__ out)
{
  const int b = blockIdx.x, tid = threadIdx.x;
  const float n1 = (float)(np[0] + 1);
  const float inv = 1.0f / (n1 + 1.0f);
  const float* AWZT = coef;
  const float* APT  = coef + 33 * NL;
  const float* ACZT = coef + 66 * NL;

  if (b < 1024) {
    const int k = b * 256 + tid;
    float xv = x[k], mv = mux[k];
    float mn = (mv * n1 + xv) * inv;
    out[OUT_MU_X + k] = mn;
    float accW[32], accP[32];
#pragma unroll
    for (int i = 0; i < 32; ++i) accW[i] = Wz[(size_t)i * NF + k];
#pragma unroll
    for (int i = 0; i < 32; ++i) accP[i] = 0.f;
    {
      float B0 = xv - mn;
#pragma unroll
      for (int i = 0; i < 32; ++i) {
        accW[i] += AWZT[i] * B0;
        accP[i] += APT[i] * B0;
      }
    }
#pragma unroll 4
    for (int j = 1; j < 33; ++j) {
      float Bj = P[(size_t)(j - 1) * NF + k];
      const float* cw = AWZT + j * 32;
      const float* cp = APT + j * 32;
#pragma unroll
      for (int i = 0; i < 32; ++i) {
        accW[i] += cw[i] * Bj;
        accP[i] += cp[i] * Bj;
      }
    }
#pragma unroll
    for (int i = 0; i < 32; ++i) out[OUT_WZ + (size_t)i * NF + k] = accW[i];
#pragma unroll
    for (int i = 0; i < 32; ++i) out[OUT_P + (size_t)i * NF + k] = accP[i];
  } else {
    const int k = (b - 1024) * 256 + tid;
    float yv = y[k], mv = muy[k];
    float mn = (mv * n1 + yv) * inv;
    out[OUT_MU_Y + k] = mn;
    float accC[32];
#pragma unroll
    for (int i = 0; i < 32; ++i) accC[i] = 0.f;
    {
      float B0 = yv - mn;
#pragma unroll
      for (int i = 0; i < 32; ++i) accC[i] += ACZT[i] * B0;
    }
#pragma unroll 4
    for (int j = 1; j < 33; ++j) {
      float Bj = Cz[(size_t)(j - 1) * NT + k];
      const float* cc = ACZT + j * 32;
#pragma unroll
      for (int i = 0; i < 32; ++i) accC[i] += cc[i] * Bj;
    }
#pragma unroll
    for (int i = 0; i < 32; ++i) out[OUT_CZ + (size_t)i * NT + k] = accC[i];
  }
}

extern "C" void kernel_launch(void* const* d_in, const int* in_sizes, int n_in,
                              void* d_out, int out_size, void* d_ws, size_t ws_size,
                              hipStream_t stream) {
  const float* x   = (const float*)d_in[0];
  const float* y   = (const float*)d_in[1];
  const float* mux = (const float*)d_in[2];
  const float* muy = (const float*)d_in[3];
  const float* u   = (const float*)d_in[4];
  const float* Wz  = (const float*)d_in[5];
  const float* Cz  = (const float*)d_in[6];
  const float* tss = (const float*)d_in[7];
  const float* bz  = (const float*)d_in[8];
  const float* P   = (const float*)d_in[9];
  const int*   n   = (const int*)d_in[10];
  float* ws  = (float*)d_ws;
  float* out = (float*)d_out;

  // slots + GY + GX + counter: contiguous, all atomically accumulated
  hipMemsetAsync(ws, 0, (size_t)(NSLOT * PBE + GYS * GYS + PBE + 4) * sizeof(float), stream);
  gram_kernel<<<NBX + 32, 320, 0, stream>>>(x, y, mux, muy, Wz, Cz, P, n, ws);
  redsolve_kernel<<<72, 256, 0, stream>>>(ws, u, tss, bz, ws + WS_COEF, out);
  out_kernel<<<1024 + 32, 256, 0, stream>>>(x, y, mux, muy, Wz, Cz, P, n, ws + WS_COEF, out);
}

// Round 7
// 208.663 us; speedup vs baseline: 1.2764x; 1.0561x over previous
//
#include <hip/hip_runtime.h>

// IPLS partial_fit (n > BURN_IN). Gram-reformulated.
// R13 = R11 with the y-side loader bug fixed. R11's y-side 128-col window
// needs 36 rows x 32 float4 = 1152 staged items (row=idx>>5, c4=idx&31); the
// failed version staged 576 with row=idx>>4 -> cols 64..127 of LDS were
// garbage -> GY garbage -> absmax 1.3e4. x-side re-audited clean.
// Design (from R11): occupancy pinned at ~1 block/CU (5 waves = 16%) every
// round; LDS/block suspected limiter. (a) CHK 128->64: x-side LDS 41.5->20.6KB,
// NCHK=8, NBX=512, same per-chunk MFMA geometry (s-steps 2), v[4] staging so
// the T14 pipeline survives regalloc. (b) y-side 128-col windows (64 blocks,
// 19KB) so smem stays small. (c) x partials: plain stores (R8-proven).
// (d) fused reduce+solve (R10-proven). (e) out_kernel j-unroll 8.

#define NF 262144
#define NT 8192
#define NL 32
#define GYS 36
#define LDSWY 132      // y-side row stride (floats): 128 + 4 pad

#define NBX 512        // x-side K-slice blocks
#define NBY 64         // y-side blocks (128-col windows)
#define KS  512        // K elems per x block
#define CHK 64         // K elems per chunk (LDS resident)
#define NCHK 8
#define GXW 68         // Gram row stride (cols 0..64 used)
#define PBE 2276       // per-block partial: 33*68 + 32 diag
#define DIAG 2244      // 33*68

#define WS_PART 0
#define WS_GY   (NBX*PBE)            // 1165312
#define WS_GX   (WS_GY + GYS*GYS)    // 1166608
#define WS_CNT  (WS_GX + PBE)        // 1168884 (int counter)
#define WS_COEF (WS_CNT + 4)         // 1168888 (+3168 -> 4.69MB, R8-proven size)

#define OUT_MU_X 0
#define OUT_MU_Y 262144
#define OUT_U    270336
#define OUT_WZ   270368
#define OUT_CZ   8658976
#define OUT_TSS  8921120
#define OUT_BZ   8921152
#define OUT_P    8921184

typedef __attribute__((ext_vector_type(8))) short bf16x8;
typedef __attribute__((ext_vector_type(4))) float f32x4;

__device__ __forceinline__ float4 ld4(const float* p) { return *(const float4*)p; }

__device__ __forceinline__ unsigned int f2bf_rne(float f) {
  unsigned int t = __float_as_uint(f);
  t += 0x7FFFu + ((t >> 16) & 1u);
  return t >> 16;
}

// f64 rsqrt: v_rsq_f64 seed (~2^-23) + one Newton step -> ~3e-14 relative.
__device__ __forceinline__ double rsq64(double x) {
  double r = __builtin_amdgcn_rsq(x);
  r = r * (1.5 - 0.5 * x * r * r);
  return r;
}

__global__ __launch_bounds__(320) void gram_kernel(
    const float* __restrict__ x, const float* __restrict__ y,
    const float* __restrict__ mux, const float* __restrict__ muy,
    const float* __restrict__ Wz, const float* __restrict__ Cz,
    const float* __restrict__ P, const int* __restrict__ np,
    float* __restrict__ ws)
{
  // x-side: hi plane 80x64 bf16 (10240B) + lo plane (10240B) + sdiag (128B)
  // y-side alias: 36 rows x 132 floats = 19008B
  __shared__ __align__(16) char smem[20608];
  const int tid = threadIdx.x;
  const int b = blockIdx.x;
  const float n1 = (float)(np[0] + 1);
  const float cmu = n1 / (n1 + 1.0f);   // xc = cmu*(x - mu_old)

  if (b < NBX) {
    // ---- x-side: bf16-split MFMA SYRK slice (CHK=64, 8 chunks) ----
    char* hB = smem;                        // hi plane: [80][64] bf16
    char* lB = smem + 80 * CHK * 2;         // lo plane
    float* sdiag = (float*)(smem + 80 * CHK * 4);
    float* PB = ws + WS_PART + (size_t)b * PBE;

    if (tid < 32) sdiag[tid] = 0.f;
    {  // zero pad rows 65..79 (both planes): words [2080, 2560)
      unsigned int* hz = (unsigned int*)hB;
      unsigned int* lz = (unsigned int*)lB;
      for (int i = tid; i < 480; i += 320) { hz[2080 + i] = 0u; lz[2080 + i] = 0u; }
    }
    __syncthreads();   // init visible before any convert's sdiag atomics

    f32x4 acc0 = {0.f, 0.f, 0.f, 0.f};
    f32x4 acc1 = acc0, acc2 = acc0;
    const int lane = tid & 63;
    const int w = tid >> 6;            // wave = N-tile 0..4 (cols w*16..w*16+15)
    const int col16 = lane & 15;
    const int kgrp = lane >> 4;        // 0..3
    const int swz = (col16 & 7) << 4;  // (row&7)<<4; row%8 == col16%8 for all frags

    float4 v[4]; float4 vm0;           // one live staging set (16+4 VGPRs)

    // 65 rows x 16 float4 = 1040 loads per chunk; <=4 per thread
    auto issue = [&](int c) {
      const int kb = b * KS + c * CHK;
#pragma unroll
      for (int it = 0; it < 4; ++it) {
        int idx = tid + it * 320;
        if (idx < 1040) {
          int row = idx >> 4;
          int c4 = idx & 15;
          int k = kb + c4 * 4;
          const float* bp = (row == 0) ? (x + k)
                          : (row < 33) ? (P + (size_t)(row - 1) * NF + k)
                                       : (Wz + (size_t)(row - 33) * NF + k);
          v[it] = ld4(bp);
          if (it == 0 && row == 0) vm0 = ld4(mux + k);
        }
      }
    };

    // staged regs -> bf16 hi/lo planes; Wz rows: 16-lane shfl-reduce -> sdiag
    auto convert_write = [&]() {
#pragma unroll
      for (int it = 0; it < 4; ++it) {
        int idx = tid + it * 320;
        if (idx < 1040) {
          int row = idx >> 4;
          int c4 = idx & 15;
          float4 t4 = v[it];
          if (it == 0 && row == 0) {
            t4.x = cmu * (t4.x - vm0.x); t4.y = cmu * (t4.y - vm0.y);
            t4.z = cmu * (t4.z - vm0.z); t4.w = cmu * (t4.w - vm0.w);
          }
          if (row >= 33) {   // 16 consecutive lanes share one Wz row
            float sq = t4.x * t4.x + t4.y * t4.y + t4.z * t4.z + t4.w * t4.w;
            sq += __shfl_xor(sq, 1, 64);
            sq += __shfl_xor(sq, 2, 64);
            sq += __shfl_xor(sq, 4, 64);
            sq += __shfl_xor(sq, 8, 64);
            if ((tid & 15) == 0) atomicAdd(&sdiag[row - 33], sq);
          }
          unsigned int b0 = __float_as_uint(t4.x), b1 = __float_as_uint(t4.y);
          unsigned int b2 = __float_as_uint(t4.z), b3 = __float_as_uint(t4.w);
          float h0 = __uint_as_float(b0 & 0xFFFF0000u);
          float h1 = __uint_as_float(b1 & 0xFFFF0000u);
          float h2 = __uint_as_float(b2 & 0xFFFF0000u);
          float h3 = __uint_as_float(b3 & 0xFFFF0000u);
          uint2 hw, lw;
          hw.x = (b0 >> 16) | ((b1 >> 16) << 16);
          hw.y = (b2 >> 16) | ((b3 >> 16) << 16);
          lw.x = f2bf_rne(t4.x - h0) | (f2bf_rne(t4.y - h1) << 16);
          lw.y = f2bf_rne(t4.z - h2) | (f2bf_rne(t4.w - h3) << 16);
          int off = ((row << 7) + (c4 << 3)) ^ ((row & 7) << 4);
          *(uint2*)(hB + off) = hw;
          *(uint2*)(lB + off) = lw;
        }
      }
    };

    auto compute_chunk = [&]() {
#pragma unroll
      for (int s = 0; s < 2; ++s) {
        const int kbyte = s * 64 + kgrp * 16;
        const int oa = ((col16 << 7) + kbyte) ^ swz;   // M-tile 0 (rows 0..15)
        const int ob = oa + (w << 11);                 // N-tile w (+w*16 rows)
        bf16x8 bh = *(const bf16x8*)(hB + ob);
        bf16x8 bl = *(const bf16x8*)(lB + ob);
        bf16x8 a0h = *(const bf16x8*)(hB + oa);
        bf16x8 a0l = *(const bf16x8*)(lB + oa);
        acc0 = __builtin_amdgcn_mfma_f32_16x16x32_bf16(a0h, bh, acc0, 0, 0, 0);
        acc0 = __builtin_amdgcn_mfma_f32_16x16x32_bf16(a0h, bl, acc0, 0, 0, 0);
        acc0 = __builtin_amdgcn_mfma_f32_16x16x32_bf16(a0l, bh, acc0, 0, 0, 0);
        acc0 = __builtin_amdgcn_mfma_f32_16x16x32_bf16(a0l, bl, acc0, 0, 0, 0);
        bf16x8 a1h = *(const bf16x8*)(hB + oa + 2048);  // rows 16..31
        bf16x8 a1l = *(const bf16x8*)(lB + oa + 2048);
        acc1 = __builtin_amdgcn_mfma_f32_16x16x32_bf16(a1h, bh, acc1, 0, 0, 0);
        acc1 = __builtin_amdgcn_mfma_f32_16x16x32_bf16(a1h, bl, acc1, 0, 0, 0);
        acc1 = __builtin_amdgcn_mfma_f32_16x16x32_bf16(a1l, bh, acc1, 0, 0, 0);
        acc1 = __builtin_amdgcn_mfma_f32_16x16x32_bf16(a1l, bl, acc1, 0, 0, 0);
        bf16x8 a2h = *(const bf16x8*)(hB + oa + 4096);  // rows 32..47 (row 32 = P31)
        bf16x8 a2l = *(const bf16x8*)(lB + oa + 4096);
        acc2 = __builtin_amdgcn_mfma_f32_16x16x32_bf16(a2h, bh, acc2, 0, 0, 0);
        acc2 = __builtin_amdgcn_mfma_f32_16x16x32_bf16(a2h, bl, acc2, 0, 0, 0);
        acc2 = __builtin_amdgcn_mfma_f32_16x16x32_bf16(a2l, bh, acc2, 0, 0, 0);
        acc2 = __builtin_amdgcn_mfma_f32_16x16x32_bf16(a2l, bl, acc2, 0, 0, 0);
      }
    };

    // R8-proven pipeline, 8 chunks: issue(c+1) right after the post-convert
    // barrier so its HBM latency hides under compute(c).
    issue(0);
    convert_write();
    __syncthreads();
    issue(1);
    compute_chunk();                   // chunk 0
    for (int c = 1; c < NCHK; ++c) {
      __syncthreads();                 // prev compute done before overwrite
      convert_write();
      __syncthreads();
      if (c + 1 < NCHK) issue(c + 1);
      compute_chunk();
    }

    // partial store (private slot): D layout col=lane&15, row=(lane>>4)*4+reg
    const int vcol = w * 16 + col16;
    if (vcol < 65) {
#pragma unroll
      for (int r2 = 0; r2 < 4; ++r2) {
        int u = kgrp * 4 + r2;
        PB[u * GXW + vcol] = acc0[r2];              // rows 0..15
        PB[(16 + u) * GXW + vcol] = acc1[r2];       // rows 16..31
      }
      if (kgrp == 0) PB[32 * GXW + vcol] = acc2[0]; // row 32 only
    }
    if (tid < 32) PB[DIAG + tid] = sdiag[tid];      // drained by last barrier
  } else {
    // ---- y-side: 36 rows [yc, Cz_0..31, 0,0,0] over a 128-col window ----
    // 36 rows x 32 float4 = 1152 staged items (row=idx>>5, c4=idx&31).
    float* lds = (float*)smem;   // 36*132*4 = 19008B
    float* GY = ws + WS_GY;
    const int yb = b - NBX;
    int gu = 0, gv = 0; bool active = (tid < 45);
    if (active) {
      int pp = tid;
      for (int g = 0; g < 9; ++g) {
        int cnt = 9 - g;
        if (pp < cnt) { gu = g; gv = g + pp; break; }
        pp -= cnt;
      }
    }
    float acc[16];
#pragma unroll
    for (int i = 0; i < 16; ++i) acc[i] = 0.f;
    const int wb = yb * 128;
    float4 vy[4]; float4 vmy;
#pragma unroll
    for (int it = 0; it < 4; ++it) {
      int idx = tid + it * 320;
      if (idx < 1152) {
        int row = idx >> 5;
        int c4 = idx & 31;
        int k = wb + c4 * 4;
        if (row == 0) {
          vy[it] = ld4(y + k);
          if (it == 0) vmy = ld4(muy + k);
        } else if (row < 33) {
          vy[it] = ld4(Cz + (size_t)(row - 1) * NT + k);
        } else {
          vy[it] = make_float4(0.f, 0.f, 0.f, 0.f);
        }
      }
    }
#pragma unroll
    for (int it = 0; it < 4; ++it) {
      int idx = tid + it * 320;
      if (idx < 1152) {
        int row = idx >> 5;
        int c4 = idx & 31;
        float4 t4 = vy[it];
        if (it == 0 && row == 0) {
          t4.x = cmu * (t4.x - vmy.x); t4.y = cmu * (t4.y - vmy.y);
          t4.z = cmu * (t4.z - vmy.z); t4.w = cmu * (t4.w - vmy.w);
        }
        *(float4*)&lds[row * LDSWY + c4 * 4] = t4;
      }
    }
    __syncthreads();
    if (active) {
      const int ub = 4 * gu * LDSWY, vb = 4 * gv * LDSWY;
      for (int c = 0; c < 32; ++c) {
        float4 av[4], bv[4];
#pragma unroll
        for (int r = 0; r < 4; ++r) av[r] = *(const float4*)&lds[ub + r * LDSWY + c * 4];
#pragma unroll
        for (int s = 0; s < 4; ++s) bv[s] = *(const float4*)&lds[vb + s * LDSWY + c * 4];
#pragma unroll
        for (int r = 0; r < 4; ++r)
#pragma unroll
          for (int s = 0; s < 4; ++s)
            acc[r * 4 + s] += av[r].x * bv[s].x + av[r].y * bv[s].y +
                              av[r].z * bv[s].z + av[r].w * bv[s].w;
      }
#pragma unroll
      for (int r = 0; r < 4; ++r)
#pragma unroll
        for (int s = 0; s < 4; ++s) {
          int u = 4 * gu + r, v = 4 * gv + s;
          if (u < 33 && v < 33) {
            float val = acc[r * 4 + s];
            atomicAdd(&GY[u * GYS + v], val);
            if (gu != gv) atomicAdd(&GY[v * GYS + u], val);
          }
        }
    }
  }
}

// One wave: f64 scalar recurrences for all 32 components (rsq64 chain).
__device__ __forceinline__ void solve_body(
    const float* __restrict__ ws, const float* __restrict__ u_in,
    const float* __restrict__ tss_in, const float* __restrict__ bz_in,
    float* __restrict__ coef, float* __restrict__ out)
{
  const int l = threadIdx.x;  // 0..63
  const float* GX = ws + WS_GX;
  const float* GY = ws + WS_GY;
  float* AWZT = coef;               // 33 x 32
  float* APT  = coef + 33 * NL;     // 33 x 32 (+P_i identity folded)
  float* ACZT = coef + 66 * NL;     // 33 x 32 (+Cz_i identity folded)

  float rP[32], rW[32], rC[32];
#pragma unroll
  for (int i = 0; i < 32; ++i) rP[i] = GX[(1 + i) * GXW + 1 + l];
#pragma unroll
  for (int i = 0; i < 32; ++i) rW[i] = (l < 32) ? GX[(1 + i) * GXW + 33 + l] : 0.f;
#pragma unroll
  for (int i = 0; i < 32; ++i) rC[i] = GY[(1 + i) * GYS + 1 + l];
  float dS  = (l < 32) ? GX[DIAG + l] : 0.f;  // ||Wz_l||^2
  float u0l = (l < 32) ? u_in[l]   : 0.f;
  float t0l = (l < 32) ? tss_in[l] : 0.f;
  float b0l = (l < 32) ? bz_in[l]  : 0.f;

  double q = (double)GX[0];                       // ||xr||^2
  double r = (double)GY[0];                       // ||yr||^2
  double pj = (l < 32) ? (double)GX[1 + l]  : 0.0;
  double wj = (l < 32) ? (double)GX[33 + l] : 0.0;
  double ej = (l < 32) ? (double)GY[1 + l]  : 0.0;
  double cx = (l == 0) ? 1.0 : 0.0;
  double cy = (l == 0) ? 1.0 : 0.0;

#pragma unroll
  for (int i = 0; i < NL; ++i) {
    double a  = __shfl(wj, i, 64);
    double g  = __shfl(ej, i, 64);
    double pi = __shfl(pj, i, 64);
    double s  = (double)__shfl(dS, i, 64);
    double h  = (double)__shfl(rC[i], i, 64);      // GY diag (1+i,1+i)
    double Pd = (double)__shfl(rP[i], i, 64);      // GX diag (1+i,1+i)
    double u0   = (double)__shfl(u0l, i, 64);
    double tss0 = (double)__shfl(t0l, i, 64);
    double bz0  = (double)__shfl(b0l, i, 64);

    double ui = u0, u1 = 0.0, tz = 0.0, tss_ = 0.0, t = 0.0;
    double rt = 0.0, rn = 0.0;
#pragma unroll
    for (int pass = 0; pass < 2; ++pass) {
      double num = a + ui * q;
      double s2  = s + 2.0 * ui * a + ui * ui * q;
      double rs  = rsq64(s2);
      tz = num * rs * (1.0 - 1e-7 * rs);     // num/(sqrt(s2)+eps) to ~2e-10
      tss_ = tss0 + tz * tz;
      rt = rsq64(tss_);
      t  = tz * rt;
      double ncz2 = h + 2.0 * t * g + t * t * r;
      rn = rsq64(ncz2);
      ui = (g + t * r) * rn;
      if (pass == 0) u1 = ui;
    }
    double u2 = ui;
    double bz_new = bz0 + u2 * tz;
    double bb = bz_new * rt;             // bz_new / sqrt(tss_)
    double phi = 1.0 - t * t;            // xr' = phi*xr - t*P_i
    double gam = bb * t * rn;            // yr' = psi*yr - gam*Cz_i
    double psi = 1.0 - gam * t;

    if (l == 0) {
      out[OUT_U + i]   = (float)u2;
      out[OUT_TSS + i] = (float)tss_;
      out[OUT_BZ + i]  = (float)bz_new;
    }
    if (l < 33) {
      AWZT[l * 32 + i] = (float)(u1 * cx);
      APT [l * 32 + i] = (float)(t  * cx) + ((l == 1 + i) ? 1.0f : 0.0f);
      ACZT[l * 32 + i] = (float)(t  * cy) + ((l == 1 + i) ? 1.0f : 0.0f);
    }
    q = phi * phi * q - 2.0 * phi * t * pi + t * t * Pd;
    r = psi * psi * r - 2.0 * psi * gam * g + gam * gam * h;
    cx *= phi; if (l == 1 + i) cx -= t;
    cy *= psi; if (l == 1 + i) cy -= gam;
    if (l < 32) {
      pj = phi * pj - t * (double)rP[i];
      wj = phi * wj - t * (double)rW[i];
      ej = psi * ej - gam * (double)rC[i];
    }
  }
}

// fused reduce (512 partials -> GX, 8 chunks x 9 eblocks, depth-8 atomics)
// + last-block inline solve (threadfence + completion counter).
__global__ __launch_bounds__(256) void redsolve_kernel(
    float* __restrict__ ws, const float* __restrict__ u_in,
    const float* __restrict__ tss_in, const float* __restrict__ bz_in,
    float* __restrict__ coef, float* __restrict__ out)
{
  const int e = (blockIdx.x % 9) * 256 + threadIdx.x;
  const int c = blockIdx.x / 9;          // 0..7
  if (e < PBE) {
    const float* PB = ws + WS_PART + (size_t)(c * 64) * PBE + e;
    float s0 = 0.f, s1 = 0.f, s2 = 0.f, s3 = 0.f;
#pragma unroll
    for (int j = 0; j < 64; j += 4) {
      s0 += PB[(size_t)j * PBE];
      s1 += PB[(size_t)(j + 1) * PBE];
      s2 += PB[(size_t)(j + 2) * PBE];
      s3 += PB[(size_t)(j + 3) * PBE];
    }
    atomicAdd(ws + WS_GX + e, (s0 + s1) + (s2 + s3));
  }
  __threadfence();                       // release: GX adds visible device-wide
  __shared__ int lastflag;
  if (threadIdx.x == 0) {
    int old = atomicAdd((int*)(ws + WS_CNT), 1);
    lastflag = (old == 71);
  }
  __syncthreads();
  if (!lastflag) return;
  __threadfence();                       // acquire: see all blocks' GX adds
  if (threadIdx.x < 64) solve_body(ws, u_in, tss_in, bz_in, coef, out);
}

// j-outer, 64 resident f32 accumulators per thread; unroll 8 -> 8 loads in flight.
__global__ __launch_bounds__(256) void out_kernel(
    const float* __restrict__ x, const float* __restrict__ y,
    const float* __restrict__ mux, const float* __restrict__ muy,
    const float* __restrict__ Wz, const float* __restrict__ Cz,
    const float* __restrict__ P, const int* __restrict__ np,
    const float* __restrict__ coef, float* __restrict__ out)
{
  const int b = blockIdx.x, tid = threadIdx.x;
  const float n1 = (float)(np[0] + 1);
  const float inv = 1.0f / (n1 + 1.0f);
  const float* AWZT = coef;
  const float* APT  = coef + 33 * NL;
  const float* ACZT = coef + 66 * NL;

  if (b < 1024) {
    const int k = b * 256 + tid;
    float xv = x[k], mv = mux[k];
    float mn = (mv * n1 + xv) * inv;
    out[OUT_MU_X + k] = mn;
    float accW[32], accP[32];
#pragma unroll
    for (int i = 0; i < 32; ++i) accW[i] = Wz[(size_t)i * NF + k];
#pragma unroll
    for (int i = 0; i < 32; ++i) accP[i] = 0.f;
    {
      float B0 = xv - mn;
#pragma unroll
      for (int i = 0; i < 32; ++i) {
        accW[i] += AWZT[i] * B0;
        accP[i] += APT[i] * B0;
      }
    }
#pragma unroll 8
    for (int j = 1; j < 33; ++j) {
      float Bj = P[(size_t)(j - 1) * NF + k];
      const float* cw = AWZT + j * 32;
      const float* cp = APT + j * 32;
#pragma unroll
      for (int i = 0; i < 32; ++i) {
        accW[i] += cw[i] * Bj;
        accP[i] += cp[i] * Bj;
      }
    }
#pragma unroll
    for (int i = 0; i < 32; ++i) out[OUT_WZ + (size_t)i * NF + k] = accW[i];
#pragma unroll
    for (int i = 0; i < 32; ++i) out[OUT_P + (size_t)i * NF + k] = accP[i];
  } else {
    const int k = (b - 1024) * 256 + tid;
    float yv = y[k], mv = muy[k];
    float mn = (mv * n1 + yv) * inv;
    out[OUT_MU_Y + k] = mn;
    float accC[32];
#pragma unroll
    for (int i = 0; i < 32; ++i) accC[i] = 0.f;
    {
      float B0 = yv - mn;
#pragma unroll
      for (int i = 0; i < 32; ++i) accC[i] += ACZT[i] * B0;
    }
#pragma unroll 8
    for (int j = 1; j < 33; ++j) {
      float Bj = Cz[(size_t)(j - 1) * NT + k];
      const float* cc = ACZT + j * 32;
#pragma unroll
      for (int i = 0; i < 32; ++i) accC[i] += cc[i] * Bj;
    }
#pragma unroll
    for (int i = 0; i < 32; ++i) out[OUT_CZ + (size_t)i * NT + k] = accC[i];
  }
}

extern "C" void kernel_launch(void* const* d_in, const int* in_sizes, int n_in,
                              void* d_out, int out_size, void* d_ws, size_t ws_size,
                              hipStream_t stream) {
  const float* x   = (const float*)d_in[0];
  const float* y   = (const float*)d_in[1];
  const float* mux = (const float*)d_in[2];
  const float* muy = (const float*)d_in[3];
  const float* u   = (const float*)d_in[4];
  const float* Wz  = (const float*)d_in[5];
  const float* Cz  = (const float*)d_in[6];
  const float* tss = (const float*)d_in[7];
  const float* bz  = (const float*)d_in[8];
  const float* P   = (const float*)d_in[9];
  const int*   n   = (const int*)d_in[10];
  float* ws  = (float*)d_ws;
  float* out = (float*)d_out;

  // GY (atomics) + GX (atomic-reduced) + counter: contiguous -> one memset
  hipMemsetAsync(ws + WS_GY, 0, (size_t)(GYS * GYS + PBE + 4) * sizeof(float), stream);
  gram_kernel<<<NBX + NBY, 320, 0, stream>>>(x, y, mux, muy, Wz, Cz, P, n, ws);
  redsolve_kernel<<<72, 256, 0, stream>>>(ws, u, tss, bz, ws + WS_COEF, out);
  out_kernel<<<1024 + 32, 256, 0, stream>>>(x, y, mux, muy, Wz, Cz, P, n, ws + WS_COEF, out);
}